// Round 3
// baseline (279.440 us; speedup 1.0000x reference)
//
#include <hip/hip_runtime.h>
#include <hip/hip_bf16.h>

#define D_MODEL 1024
#define NHEAD   16
#define HEAD_DIM 64
#define BATCH   2
#define SEQ     2048
#define NTOK    (BATCH*SEQ)   // 4096

// log2(10000)/64
#define FREQ_LOG2 0.20762050593046015f

typedef short  bfrag __attribute__((ext_vector_type(8)));  // 8 bf16 = 4 VGPR
typedef float  ffrag __attribute__((ext_vector_type(4)));  // C/D frag

__device__ inline ushort f2bf(float x) {
    __hip_bfloat16 h = __float2bfloat16(x);
    return __builtin_bit_cast(ushort, h);
}
__device__ inline void split_bf(float x, ushort& hi, ushort& lo) {
    __hip_bfloat16 h = __float2bfloat16(x);
    hi = __builtin_bit_cast(ushort, h);
    lo = f2bf(x - __bfloat162float(h));
}

// async global->LDS DMA, 16B per lane (lds dest = uniform base + lane*16)
__device__ inline void gload16(const ushort* g, ushort* l) {
    __builtin_amdgcn_global_load_lds(
        (const __attribute__((address_space(1))) void*)g,
        (__attribute__((address_space(3))) void*)l, 16, 0, 0);
}

// ---------------------------------------------------------------------------
// Pre-pass 1: split data -> Ahi, Alo  (bf16 hi/lo), [4096][1024]
// ---------------------------------------------------------------------------
__global__ __launch_bounds__(256)
void split_data(const float* __restrict__ x, ushort* __restrict__ hi,
                ushort* __restrict__ lo)
{
    const int i4 = (blockIdx.x * 256 + threadIdx.x) * 4;
    const float4 v = *(const float4*)(x + i4);
    ushort4 h, l;
    split_bf(v.x, h.x, l.x); split_bf(v.y, h.y, l.y);
    split_bf(v.z, h.z, l.z); split_bf(v.w, h.w, l.w);
    *(ushort4*)(hi + i4) = h;
    *(ushort4*)(lo + i4) = l;
}

// ---------------------------------------------------------------------------
// Pre-pass 2: W[k][n] -> WT[n][k], plain bf16.  grid (16,16,3)
// ---------------------------------------------------------------------------
__global__ __launch_bounds__(256)
void split_tr_w(const float* __restrict__ Wq, const float* __restrict__ Wk,
                const float* __restrict__ Wv, ushort* __restrict__ hi)
{
    const int z = blockIdx.z;
    const float* W = (z == 0) ? Wq : (z == 1) ? Wk : Wv;
    ushort* thi = hi + (size_t)z * D_MODEL * D_MODEL;

    __shared__ float T[64][65];
    const int t  = threadIdx.x;
    const int k0 = blockIdx.x * 64, n0 = blockIdx.y * 64;

    #pragma unroll
    for (int i = 0; i < 4; i++) {
        const int f = i * 256 + t, r = f >> 4, c = (f & 15) * 4;
        const float4 v = *(const float4*)(W + (size_t)(k0 + r) * D_MODEL + n0 + c);
        T[r][c] = v.x; T[r][c + 1] = v.y; T[r][c + 2] = v.z; T[r][c + 3] = v.w;
    }
    __syncthreads();
    #pragma unroll
    for (int i = 0; i < 4; i++) {
        const int f = i * 256 + t, nr = f >> 4, kc = (f & 15) * 4;
        ushort4 h;
        h.x = f2bf(T[kc + 0][nr]);
        h.y = f2bf(T[kc + 1][nr]);
        h.z = f2bf(T[kc + 2][nr]);
        h.w = f2bf(T[kc + 3][nr]);
        const size_t o = (size_t)(n0 + nr) * D_MODEL + k0 + kc;
        *(ushort4*)(thi + o) = h;
    }
}

// ---------------------------------------------------------------------------
// Kernel 3: bf16x2 GEMM 128x128xBK32 + bias + RoPE epilogue.
// global_load_lds width-16 into linear double-buffered LDS, 2-phase prefetch,
// ONE barrier per K-step.  LDS layout is chunk-XOR swizzled (rule #21):
//   physical 16B-chunk = logical chunk ^ ((row>>1)&3)
// applied identically on the DMA *source* address (per-lane) and the
// fragment *read* address -> ds_read_b128 is 2-way (free) instead of 8-way.
// z=0 -> Q hi/lo (pre-scaled 1/8); z=1 -> K hi only; z=2 -> VT bf16.
// ---------------------------------------------------------------------------
#define BK 32   // K-step; one LDS row = 32 bf16 = 64B = 4 chunks of 16B

union GemmSM {
    ushort st[2][3][128 * BK];   // [buf][ahi,alo,bhi][row*BK+col]  = 48 KB
    float  c[64 * 132];          // epilogue scratch (33.8 KB)
};

__global__ __launch_bounds__(256, 3)
void gemm_qkv(const ushort* __restrict__ Ahi, const ushort* __restrict__ Alo,
              const ushort* __restrict__ WThi,
              const float* __restrict__ bq, const float* __restrict__ bk,
              const float* __restrict__ bv, const float* __restrict__ temporal,
              ushort* __restrict__ Qhi, ushort* __restrict__ Qlo,
              ushort* __restrict__ Khi,
              ushort* __restrict__ VT)
{
    __shared__ GemmSM sm;
    const int z  = blockIdx.z;
    const int m0 = blockIdx.x * 128;
    const int n0 = blockIdx.y * 128;
    const float* bias = (z == 0) ? bq : (z == 1) ? bk : bv;
    const ushort* Bh = WThi + (size_t)z * D_MODEL * D_MODEL;

    const int t = threadIdx.x;
    const int w = t >> 6, lane = t & 63;
    const int lane15 = lane & 15, quad8 = (lane >> 4) * 8, quad = lane >> 4;
    const int wm = (w >> 1) * 64, wn = (w & 1) * 64;

    ffrag acc[4][4];
    #pragma unroll
    for (int i = 0; i < 4; i++)
        #pragma unroll
        for (int j = 0; j < 4; j++) acc[i][j] = (ffrag){0.f, 0.f, 0.f, 0.f};

    // DMA staging: lane i of a 16-row chunk covers row (i>>2); its LDS slot is
    // physical chunk (i&3), so it must FETCH logical chunk (i&3)^((i>>3)&3)
    // (rb is a multiple of 16, so (row>>1)&3 == (i>>3)&3).
    const int wr = w * 32;                                  // wave's 32-row slab
    const int lr = lane >> 2;                               // row within chunk
    const int lc = (((lane & 3) ^ ((lane >> 3) & 3))) * 8;  // swizzled col (elems)

    auto stage = [&](int bsel, int k0) {
        #pragma unroll
        for (int ch = 0; ch < 2; ch++) {
            const int rb = wr + ch * 16;
            const ushort* ga = Ahi + (size_t)(m0 + rb + lr) * D_MODEL + k0 + lc;
            const ushort* gl = Alo + (size_t)(m0 + rb + lr) * D_MODEL + k0 + lc;
            const ushort* gb = Bh  + (size_t)(n0 + rb + lr) * D_MODEL + k0 + lc;
            gload16(ga, &sm.st[bsel][0][rb * BK]);
            gload16(gl, &sm.st[bsel][1][rb * BK]);
            gload16(gb, &sm.st[bsel][2][rb * BK]);
        }
    };

    stage(0, 0);
    __syncthreads();    // drains vmcnt(0): buf0 ready

    // read-side swizzle: logical chunk 'quad' at row (16-aligned + lane15)
    const int rdsw = (quad ^ ((lane15 >> 1) & 3)) * 8;

    int buf = 0;
    for (int k0 = 0; k0 < D_MODEL; k0 += BK) {
        // issue next tile's async loads before computing this one
        if (k0 + BK < D_MODEL) stage(buf ^ 1, k0 + BK);

        bfrag ah[4], al[4];
        #pragma unroll
        for (int mt = 0; mt < 4; mt++) {
            ah[mt] = *(const bfrag*)&sm.st[buf][0][(wm + mt * 16 + lane15) * BK + rdsw];
            al[mt] = *(const bfrag*)&sm.st[buf][1][(wm + mt * 16 + lane15) * BK + rdsw];
        }
        #pragma unroll
        for (int nt = 0; nt < 4; nt++) {
            const bfrag bh = *(const bfrag*)&sm.st[buf][2][(wn + nt * 16 + lane15) * BK + rdsw];
            #pragma unroll
            for (int mt = 0; mt < 4; mt++) {
                ffrag a = acc[mt][nt];
                a = __builtin_amdgcn_mfma_f32_16x16x32_bf16(ah[mt], bh, a, 0, 0, 0);
                a = __builtin_amdgcn_mfma_f32_16x16x32_bf16(al[mt], bh, a, 0, 0, 0);
                acc[mt][nt] = a;
            }
        }
        __syncthreads();   // drains next-tile DMA + orders reads vs overwrite
        buf ^= 1;
    }

    float bn[4];
    #pragma unroll
    for (int nt = 0; nt < 4; nt++) bn[nt] = bias[n0 + wn + nt * 16 + lane15];

    const int CST = (z == 2) ? 129 : 132;

    #pragma unroll
    for (int p = 0; p < 2; p++) {
        if (p) __syncthreads();
        if ((w >> 1) == p) {
            #pragma unroll
            for (int mt = 0; mt < 4; mt++)
                #pragma unroll
                for (int nt = 0; nt < 4; nt++)
                    #pragma unroll
                    for (int rr = 0; rr < 4; rr++)
                        sm.c[(mt * 16 + quad * 4 + rr) * CST + wn + nt * 16 + lane15] =
                            acc[mt][nt][rr] + bn[nt];
        }
        __syncthreads();

        if (z < 2) {
            ushort* ohi = (z == 0) ? Qhi : Khi;
            const float sc = (z == 0) ? 0.125f : 1.0f;
            #pragma unroll
            for (int i = 0; i < 8; i++) {
                const int f = i * 256 + t, r = f >> 5, c4 = (f & 31) * 4;
                float4 v = *(float4*)&sm.c[r * 132 + c4];
                const int m = m0 + p * 64 + r;
                const float tv = temporal[m];
                const float fr0 = exp2f(-(float)(c4 & 63) * FREQ_LOG2);
                const float fr1 = exp2f(-(float)((c4 + 2) & 63) * FREQ_LOG2);
                float s0, c0, s1, c1v;
                __sincosf(tv * fr0, &s0, &c0);
                __sincosf(tv * fr1, &s1, &c1v);
                const float y0 = (v.x * c0 - v.y * s0) * sc;
                const float y1 = (v.y * c0 + v.x * s0) * sc;
                const float y2 = (v.z * c1v - v.w * s1) * sc;
                const float y3 = (v.w * c1v + v.z * s1) * sc;
                ushort4 h, l;
                split_bf(y0, h.x, l.x); split_bf(y1, h.y, l.y);
                split_bf(y2, h.z, l.z); split_bf(y3, h.w, l.w);
                const size_t o = (size_t)m * D_MODEL + n0 + c4;
                *(ushort4*)(ohi + o) = h;
                if (z == 0) *(ushort4*)(Qlo + o) = l;   // K needs no lo
            }
        } else {
            const int bb = m0 >> 11;
            #pragma unroll
            for (int i = 0; i < 4; i++) {
                const int cid = i * 256 + t, col = cid >> 3, tg = (cid & 7) * 8;
                ushort u8[8];
                #pragma unroll
                for (int j = 0; j < 8; j++) u8[j] = f2bf(sm.c[(tg + j) * 129 + col]);
                const int ncol = n0 + col, hh = ncol >> 6, d = ncol & 63;
                const size_t dst = ((size_t)(bb * NHEAD + hh) * HEAD_DIM + d) * SEQ +
                                   (m0 & (SEQ - 1)) + p * 64 + tg;
                *(int4*)(VT + dst) = *(int4*)u8;
            }
        }
    }
}

// ---------------------------------------------------------------------------
// Kernel 4: MFMA flash attention, streaming softmax, 64-q-row tile.
// R3 changes:
//  (a) mask values register-prefetched one KV-tile ahead (2-deep, named
//      mvA/mvB; softmax consumes registers -> no mid-iter vmcnt drain of the
//      K/V HBM prefetch loads)
//  (b) lsP is a flat [64][64] with XOR chunk swizzle
//        phys16Bchunk = chunk ^ (((row>>2)&3)<<1 | (row&1))
//      write side and read side use the same involution -> P writes go from
//      4-way bank conflict (quad pairs) to conflict-free; reads stay free.
// ---------------------------------------------------------------------------
#define KLD 72   // K/V rows 144B apart -> banks +4 mod 32 (reads 2-way free)
#define PLD 64   // P: flat rows, conflict handled by XOR swizzle

__global__ __launch_bounds__(256, 4)
void attn_mfma(const ushort* __restrict__ Qhi, const ushort* __restrict__ Qlo,
               const ushort* __restrict__ Khi,
               const ushort* __restrict__ VT,  const float* __restrict__ mask,
               float* __restrict__ out)
{
    __shared__ ushort lsK[64 * KLD], lsV[64 * KLD], lsP[64 * PLD];

    // XCD-L2 swizzle: blocks sharing one (b,h) K/V slab land on one XCD
    const int bid  = blockIdx.x;
    const int bh   = (bid & 7) * 4 + (bid >> 8);
    const int qb   = (bid >> 3) & 31;
    const int b    = bh >> 4, h = bh & 15;
    const int q0   = qb * 64;

    const int t = threadIdx.x, w = t >> 6, lane = t & 63;
    const int lane15 = lane & 15, quad = lane >> 4, quad8 = quad * 8;
    const size_t tok0 = (size_t)b * SEQ;

    // loop-invariant Q fragments (A-layout) straight from global
    bfrag qh[2], ql[2];
    const size_t qrow = (tok0 + q0 + w * 16 + lane15) * D_MODEL + h * HEAD_DIM;
    #pragma unroll
    for (int ks = 0; ks < 2; ks++) {
        qh[ks] = *(const bfrag*)(Qhi + qrow + ks * 32 + quad8);
        ql[ks] = *(const bfrag*)(Qlo + qrow + ks * 32 + quad8);
    }

    ffrag of[4];
    #pragma unroll
    for (int nt = 0; nt < 4; nt++) of[nt] = (ffrag){0.f, 0.f, 0.f, 0.f};
    float l_i[4] = {0.f, 0.f, 0.f, 0.f};

    // staging: 2 chunks/thread per array (rows 0..31 and 32..63)
    const int r1 = t >> 3,    c1 = (t & 7) * 8;
    const int r2 = 32 + r1,   c2 = c1;
    const ushort* Kh0 = Khi + tok0 * D_MODEL + h * HEAD_DIM;
    const ushort* Vt0 = VT + (size_t)(b * NHEAD + h) * HEAD_DIM * SEQ;

    int4 pk0 = *(const int4*)(Kh0 + (size_t)r1 * D_MODEL + c1);
    int4 pk1 = *(const int4*)(Kh0 + (size_t)r2 * D_MODEL + c2);
    int4 pv0 = *(const int4*)(Vt0 + (size_t)r1 * SEQ + c1);
    int4 pv1 = *(const int4*)(Vt0 + (size_t)r2 * SEQ + c2);

    const float* mrow = mask + (size_t)(q0 + w * 16 + quad * 4) * SEQ;

    // mask prefetch registers: tile 0 into mvA
    float mvA[4][4], mvB[4][4];
    #pragma unroll
    for (int nt = 0; nt < 4; nt++)
        #pragma unroll
        for (int rr = 0; rr < 4; rr++)
            mvA[nt][rr] = mrow[(size_t)rr * SEQ + nt * 16 + lane15];

    // P read-side swizzle key (row = w*16 + lane15)
    const int keyr = (((lane15 >> 2) & 3) << 1) | (lane15 & 1);

    auto STEP = [&](int kt, float (&cur)[4][4], float (&nxt)[4][4]) {
        *(int4*)&lsK[r1 * KLD + c1] = pk0;  *(int4*)&lsK[r2 * KLD + c2] = pk1;
        *(int4*)&lsV[r1 * KLD + c1] = pv0;  *(int4*)&lsV[r2 * KLD + c2] = pv1;
        __syncthreads();

        const int ktn = (kt + 64 < SEQ) ? kt + 64 : 0;

        // issue next tile's mask loads FIRST (consumed next STEP)
        #pragma unroll
        for (int nt = 0; nt < 4; nt++)
            #pragma unroll
            for (int rr = 0; rr < 4; rr++)
                nxt[nt][rr] = mrow[(size_t)rr * SEQ + ktn + nt * 16 + lane15];

        // K/V register prefetch for next tile
        pk0 = *(const int4*)(Kh0 + (size_t)(ktn + r1) * D_MODEL + c1);
        pk1 = *(const int4*)(Kh0 + (size_t)(ktn + r2) * D_MODEL + c2);
        pv0 = *(const int4*)(Vt0 + (size_t)r1 * SEQ + ktn + c1);
        pv1 = *(const int4*)(Vt0 + (size_t)r2 * SEQ + ktn + c2);

        // S = (Q/8) K^T  (qh + ql) x k
        ffrag s[4];
        #pragma unroll
        for (int nt = 0; nt < 4; nt++) {
            ffrag a = (ffrag){0.f, 0.f, 0.f, 0.f};
            #pragma unroll
            for (int ks = 0; ks < 2; ks++) {
                const bfrag kf = *(const bfrag*)&lsK[(nt * 16 + lane15) * KLD + ks * 32 + quad8];
                a = __builtin_amdgcn_mfma_f32_16x16x32_bf16(qh[ks], kf, a, 0, 0, 0);
                a = __builtin_amdgcn_mfma_f32_16x16x32_bf16(ql[ks], kf, a, 0, 0, 0);
            }
            s[nt] = a;
        }

        // streaming softmax: exp (mask from registers), P^T to swizzled LDS
        #pragma unroll
        for (int nt = 0; nt < 4; nt++) {
            #pragma unroll
            for (int rr = 0; rr < 4; rr++) {
                const float e = __expf(s[nt][rr] + cur[nt][rr]);
                l_i[rr] += e;
                const int prow = w * 16 + quad * 4 + rr;
                const int pchk = (2 * nt + (lane15 >> 3)) ^ ((quad << 1) | (rr & 1));
                lsP[prow * PLD + pchk * 8 + (lane15 & 7)] = f2bf(e);
            }
        }

        // O += P V  (P rows are wave-private: no barrier)
        #pragma unroll
        for (int ks = 0; ks < 2; ks++) {
            const bfrag pf = *(const bfrag*)&lsP[(w * 16 + lane15) * PLD +
                                                 ((ks * 4 + quad) ^ keyr) * 8];
            #pragma unroll
            for (int nt = 0; nt < 4; nt++) {
                const bfrag vf = *(const bfrag*)&lsV[(nt * 16 + lane15) * KLD + ks * 32 + quad8];
                of[nt] = __builtin_amdgcn_mfma_f32_16x16x32_bf16(pf, vf, of[nt], 0, 0, 0);
            }
        }
        __syncthreads();
    };

    for (int kt = 0; kt < SEQ; kt += 128) {
        STEP(kt,      mvA, mvB);
        STEP(kt + 64, mvB, mvA);
    }

    float inv[4];
    #pragma unroll
    for (int rr = 0; rr < 4; rr++) {
        float v = l_i[rr];
        #pragma unroll
        for (int off = 1; off < 16; off <<= 1) v += __shfl_xor(v, off);
        inv[rr] = 1.0f / v;
    }
    #pragma unroll
    for (int nt = 0; nt < 4; nt++)
        #pragma unroll
        for (int rr = 0; rr < 4; rr++)
            out[(tok0 + q0 + w * 16 + quad * 4 + rr) * D_MODEL + h * HEAD_DIM +
                nt * 16 + lane15] = of[nt][rr] * inv[rr];
}

// ---------------------------------------------------------------------------
extern "C" void kernel_launch(void* const* d_in, const int* in_sizes, int n_in,
                              void* d_out, int out_size, void* d_ws, size_t ws_size,
                              hipStream_t stream)
{
    const float* data     = (const float*)d_in[0];
    const float* temporal = (const float*)d_in[1];
    const float* mask     = (const float*)d_in[2];
    const float* Wq = (const float*)d_in[3];
    const float* bq = (const float*)d_in[4];
    const float* Wk = (const float*)d_in[5];
    const float* bk = (const float*)d_in[6];
    const float* Wv = (const float*)d_in[7];
    const float* bv = (const float*)d_in[8];
    float* out = (float*)d_out;

    char* ws = (char*)d_ws;
    const size_t MB = 1024 * 1024;
    ushort* Ahi  = (ushort*)(ws + 0 * MB);
    ushort* Alo  = (ushort*)(ws + 8 * MB);
    ushort* WThi = (ushort*)(ws + 16 * MB);   // 6 MB (3x1024x1024 bf16)
    ushort* Qhi  = (ushort*)(ws + 28 * MB);
    ushort* Qlo  = (ushort*)(ws + 36 * MB);
    ushort* Khi  = (ushort*)(ws + 44 * MB);
    ushort* VT   = (ushort*)(ws + 60 * MB);

    split_data<<<dim3(NTOK * D_MODEL / 1024), 256, 0, stream>>>(data, Ahi, Alo);
    split_tr_w<<<dim3(16, 16, 3), 256, 0, stream>>>(Wq, Wk, Wv, WThi);
    gemm_qkv<<<dim3(NTOK / 128, D_MODEL / 128, 3), 256, 0, stream>>>(
        Ahi, Alo, WThi, bq, bk, bv, temporal,
        Qhi, Qlo, Khi, VT);
    attn_mfma<<<dim3(BATCH * NHEAD * SEQ / 64), 256, 0, stream>>>(
        Qhi, Qlo, Khi, VT, mask, out);
}

// Round 4
// 262.787 us; speedup vs baseline: 1.0634x; 1.0634x over previous
//
#include <hip/hip_runtime.h>
#include <hip/hip_bf16.h>

#define D_MODEL 1024
#define NHEAD   16
#define HEAD_DIM 64
#define BATCH   2
#define SEQ     2048
#define NTOK    (BATCH*SEQ)   // 4096

// log2(10000)/64
#define FREQ_LOG2 0.20762050593046015f

typedef short  bfrag __attribute__((ext_vector_type(8)));  // 8 bf16 = 4 VGPR
typedef float  ffrag __attribute__((ext_vector_type(4)));  // C/D frag

__device__ inline ushort f2bf(float x) {
    __hip_bfloat16 h = __float2bfloat16(x);
    return __builtin_bit_cast(ushort, h);
}
__device__ inline void split_bf(float x, ushort& hi, ushort& lo) {
    __hip_bfloat16 h = __float2bfloat16(x);
    hi = __builtin_bit_cast(ushort, h);
    lo = f2bf(x - __bfloat162float(h));
}

// async global->LDS DMA, 16B per lane (lds dest = uniform base + lane*16)
__device__ inline void gload16(const ushort* g, ushort* l) {
    __builtin_amdgcn_global_load_lds(
        (const __attribute__((address_space(1))) void*)g,
        (__attribute__((address_space(3))) void*)l, 16, 0, 0);
}

// ---------------------------------------------------------------------------
// Pre-pass 1: split data -> Ahi, Alo  (bf16 hi/lo), [4096][1024]
// ---------------------------------------------------------------------------
__global__ __launch_bounds__(256)
void split_data(const float* __restrict__ x, ushort* __restrict__ hi,
                ushort* __restrict__ lo)
{
    const int i4 = (blockIdx.x * 256 + threadIdx.x) * 4;
    const float4 v = *(const float4*)(x + i4);
    ushort4 h, l;
    split_bf(v.x, h.x, l.x); split_bf(v.y, h.y, l.y);
    split_bf(v.z, h.z, l.z); split_bf(v.w, h.w, l.w);
    *(ushort4*)(hi + i4) = h;
    *(ushort4*)(lo + i4) = l;
}

// ---------------------------------------------------------------------------
// Pre-pass 2: W[k][n] -> WT[n][k], plain bf16.  grid (16,16,3)
// ---------------------------------------------------------------------------
__global__ __launch_bounds__(256)
void split_tr_w(const float* __restrict__ Wq, const float* __restrict__ Wk,
                const float* __restrict__ Wv, ushort* __restrict__ hi)
{
    const int z = blockIdx.z;
    const float* W = (z == 0) ? Wq : (z == 1) ? Wk : Wv;
    ushort* thi = hi + (size_t)z * D_MODEL * D_MODEL;

    __shared__ float T[64][65];
    const int t  = threadIdx.x;
    const int k0 = blockIdx.x * 64, n0 = blockIdx.y * 64;

    #pragma unroll
    for (int i = 0; i < 4; i++) {
        const int f = i * 256 + t, r = f >> 4, c = (f & 15) * 4;
        const float4 v = *(const float4*)(W + (size_t)(k0 + r) * D_MODEL + n0 + c);
        T[r][c] = v.x; T[r][c + 1] = v.y; T[r][c + 2] = v.z; T[r][c + 3] = v.w;
    }
    __syncthreads();
    #pragma unroll
    for (int i = 0; i < 4; i++) {
        const int f = i * 256 + t, nr = f >> 4, kc = (f & 15) * 4;
        ushort4 h;
        h.x = f2bf(T[kc + 0][nr]);
        h.y = f2bf(T[kc + 1][nr]);
        h.z = f2bf(T[kc + 2][nr]);
        h.w = f2bf(T[kc + 3][nr]);
        const size_t o = (size_t)(n0 + nr) * D_MODEL + k0 + kc;
        *(ushort4*)(thi + o) = h;
    }
}

// ---------------------------------------------------------------------------
// Kernel 3: bf16x2 GEMM 128x128xBK32 + bias + RoPE epilogue.
// global_load_lds width-16 into linear double-buffered LDS, 2-phase prefetch,
// ONE barrier per K-step.  LDS layout is chunk-XOR swizzled (rule #21):
//   physical 16B-chunk = logical chunk ^ ((row>>1)&3)
// applied identically on the DMA *source* address (per-lane) and the
// fragment *read* address -> ds_read_b128 is 2-way (free) instead of 8-way.
// z=0 -> Q hi/lo (pre-scaled 1/8); z=1 -> K hi only; z=2 -> VT bf16.
// ---------------------------------------------------------------------------
#define BK 32   // K-step; one LDS row = 32 bf16 = 64B = 4 chunks of 16B

union GemmSM {
    ushort st[2][3][128 * BK];   // [buf][ahi,alo,bhi][row*BK+col]  = 48 KB
    float  c[64 * 132];          // epilogue scratch (33.8 KB)
};

__global__ __launch_bounds__(256, 3)
void gemm_qkv(const ushort* __restrict__ Ahi, const ushort* __restrict__ Alo,
              const ushort* __restrict__ WThi,
              const float* __restrict__ bq, const float* __restrict__ bk,
              const float* __restrict__ bv, const float* __restrict__ temporal,
              ushort* __restrict__ Qhi, ushort* __restrict__ Qlo,
              ushort* __restrict__ Khi,
              ushort* __restrict__ VT)
{
    __shared__ GemmSM sm;
    const int z  = blockIdx.z;
    const int m0 = blockIdx.x * 128;
    const int n0 = blockIdx.y * 128;
    const float* bias = (z == 0) ? bq : (z == 1) ? bk : bv;
    const ushort* Bh = WThi + (size_t)z * D_MODEL * D_MODEL;

    const int t = threadIdx.x;
    const int w = t >> 6, lane = t & 63;
    const int lane15 = lane & 15, quad8 = (lane >> 4) * 8, quad = lane >> 4;
    const int wm = (w >> 1) * 64, wn = (w & 1) * 64;

    ffrag acc[4][4];
    #pragma unroll
    for (int i = 0; i < 4; i++)
        #pragma unroll
        for (int j = 0; j < 4; j++) acc[i][j] = (ffrag){0.f, 0.f, 0.f, 0.f};

    // DMA staging: lane i of a 16-row chunk covers row (i>>2); its LDS slot is
    // physical chunk (i&3), so it must FETCH logical chunk (i&3)^((i>>3)&3)
    // (rb is a multiple of 16, so (row>>1)&3 == (i>>3)&3).
    const int wr = w * 32;                                  // wave's 32-row slab
    const int lr = lane >> 2;                               // row within chunk
    const int lc = (((lane & 3) ^ ((lane >> 3) & 3))) * 8;  // swizzled col (elems)

    auto stage = [&](int bsel, int k0) {
        #pragma unroll
        for (int ch = 0; ch < 2; ch++) {
            const int rb = wr + ch * 16;
            const ushort* ga = Ahi + (size_t)(m0 + rb + lr) * D_MODEL + k0 + lc;
            const ushort* gl = Alo + (size_t)(m0 + rb + lr) * D_MODEL + k0 + lc;
            const ushort* gb = Bh  + (size_t)(n0 + rb + lr) * D_MODEL + k0 + lc;
            gload16(ga, &sm.st[bsel][0][rb * BK]);
            gload16(gl, &sm.st[bsel][1][rb * BK]);
            gload16(gb, &sm.st[bsel][2][rb * BK]);
        }
    };

    stage(0, 0);
    __syncthreads();    // drains vmcnt(0): buf0 ready

    // read-side swizzle: logical chunk 'quad' at row (16-aligned + lane15)
    const int rdsw = (quad ^ ((lane15 >> 1) & 3)) * 8;

    int buf = 0;
    for (int k0 = 0; k0 < D_MODEL; k0 += BK) {
        // issue next tile's async loads before computing this one
        if (k0 + BK < D_MODEL) stage(buf ^ 1, k0 + BK);

        bfrag ah[4], al[4];
        #pragma unroll
        for (int mt = 0; mt < 4; mt++) {
            ah[mt] = *(const bfrag*)&sm.st[buf][0][(wm + mt * 16 + lane15) * BK + rdsw];
            al[mt] = *(const bfrag*)&sm.st[buf][1][(wm + mt * 16 + lane15) * BK + rdsw];
        }
        #pragma unroll
        for (int nt = 0; nt < 4; nt++) {
            const bfrag bh = *(const bfrag*)&sm.st[buf][2][(wn + nt * 16 + lane15) * BK + rdsw];
            #pragma unroll
            for (int mt = 0; mt < 4; mt++) {
                ffrag a = acc[mt][nt];
                a = __builtin_amdgcn_mfma_f32_16x16x32_bf16(ah[mt], bh, a, 0, 0, 0);
                a = __builtin_amdgcn_mfma_f32_16x16x32_bf16(al[mt], bh, a, 0, 0, 0);
                acc[mt][nt] = a;
            }
        }
        __syncthreads();   // drains next-tile DMA + orders reads vs overwrite
        buf ^= 1;
    }

    float bn[4];
    #pragma unroll
    for (int nt = 0; nt < 4; nt++) bn[nt] = bias[n0 + wn + nt * 16 + lane15];

    const int CST = (z == 2) ? 129 : 132;

    #pragma unroll
    for (int p = 0; p < 2; p++) {
        if (p) __syncthreads();
        if ((w >> 1) == p) {
            #pragma unroll
            for (int mt = 0; mt < 4; mt++)
                #pragma unroll
                for (int nt = 0; nt < 4; nt++)
                    #pragma unroll
                    for (int rr = 0; rr < 4; rr++)
                        sm.c[(mt * 16 + quad * 4 + rr) * CST + wn + nt * 16 + lane15] =
                            acc[mt][nt][rr] + bn[nt];
        }
        __syncthreads();

        if (z < 2) {
            ushort* ohi = (z == 0) ? Qhi : Khi;
            const float sc = (z == 0) ? 0.125f : 1.0f;
            #pragma unroll
            for (int i = 0; i < 8; i++) {
                const int f = i * 256 + t, r = f >> 5, c4 = (f & 31) * 4;
                float4 v = *(float4*)&sm.c[r * 132 + c4];
                const int m = m0 + p * 64 + r;
                const float tv = temporal[m];
                const float fr0 = exp2f(-(float)(c4 & 63) * FREQ_LOG2);
                const float fr1 = exp2f(-(float)((c4 + 2) & 63) * FREQ_LOG2);
                float s0, c0, s1, c1v;
                __sincosf(tv * fr0, &s0, &c0);
                __sincosf(tv * fr1, &s1, &c1v);
                const float y0 = (v.x * c0 - v.y * s0) * sc;
                const float y1 = (v.y * c0 + v.x * s0) * sc;
                const float y2 = (v.z * c1v - v.w * s1) * sc;
                const float y3 = (v.w * c1v + v.z * s1) * sc;
                ushort4 h, l;
                split_bf(y0, h.x, l.x); split_bf(y1, h.y, l.y);
                split_bf(y2, h.z, l.z); split_bf(y3, h.w, l.w);
                const size_t o = (size_t)m * D_MODEL + n0 + c4;
                *(ushort4*)(ohi + o) = h;
                if (z == 0) *(ushort4*)(Qlo + o) = l;   // K needs no lo
            }
        } else {
            const int bb = m0 >> 11;
            #pragma unroll
            for (int i = 0; i < 4; i++) {
                const int cid = i * 256 + t, col = cid >> 3, tg = (cid & 7) * 8;
                ushort u8[8];
                #pragma unroll
                for (int j = 0; j < 8; j++) u8[j] = f2bf(sm.c[(tg + j) * 129 + col]);
                const int ncol = n0 + col, hh = ncol >> 6, d = ncol & 63;
                const size_t dst = ((size_t)(bb * NHEAD + hh) * HEAD_DIM + d) * SEQ +
                                   (m0 & (SEQ - 1)) + p * 64 + tg;
                *(int4*)(VT + dst) = *(int4*)u8;
            }
        }
    }
}

// ---------------------------------------------------------------------------
// Kernel 4: MFMA flash attention, streaming softmax, 64-q-row tile.
// R4: double-buffered K/V in flat XOR-swizzled [64][64] rows -> ONE barrier
// per KV-tile (was 2).  LDS = 2*8K(K) + 2*8K(V) + 8K(P) = 40960 B exactly
// -> 4 blocks/CU * 40960 = 160 KiB, zero occupancy loss.
// Swizzle (rule #21, register-staged both sides):
//   phys 16B-chunk = logical chunk ^ (row & 7)
// Mask loads are plain constant-indexed locals (no arrays-by-ref: rule #20).
// ---------------------------------------------------------------------------
__global__ __launch_bounds__(256, 4)
void attn_mfma(const ushort* __restrict__ Qhi, const ushort* __restrict__ Qlo,
               const ushort* __restrict__ Khi,
               const ushort* __restrict__ VT,  const float* __restrict__ mask,
               float* __restrict__ out)
{
    __shared__ ushort lsK[2][64 * 64], lsV[2][64 * 64], lsP[64 * 64];

    // XCD-L2 swizzle: blocks sharing one (b,h) K/V slab land on one XCD
    const int bid  = blockIdx.x;
    const int bh   = (bid & 7) * 4 + (bid >> 8);
    const int qb   = (bid >> 3) & 31;
    const int b    = bh >> 4, h = bh & 15;
    const int q0   = qb * 64;

    const int t = threadIdx.x, w = t >> 6, lane = t & 63;
    const int lane15 = lane & 15, quad = lane >> 4;
    const size_t tok0 = (size_t)b * SEQ;

    // loop-invariant Q fragments (A-layout) straight from global
    bfrag qh[2], ql[2];
    const size_t qrow = (tok0 + q0 + w * 16 + lane15) * D_MODEL + h * HEAD_DIM;
    #pragma unroll
    for (int ks = 0; ks < 2; ks++) {
        qh[ks] = *(const bfrag*)(Qhi + qrow + ks * 32 + quad * 8);
        ql[ks] = *(const bfrag*)(Qlo + qrow + ks * 32 + quad * 8);
    }

    ffrag of[4];
    #pragma unroll
    for (int nt = 0; nt < 4; nt++) of[nt] = (ffrag){0.f, 0.f, 0.f, 0.f};
    float l_i[4] = {0.f, 0.f, 0.f, 0.f};

    // staging: 2 chunks/thread per array (rows 0..31 and 32..63); the
    // write-side swizzle key (row&7) is identical for r1 and r1+32.
    const int r1 = t >> 3,  c1 = (t & 7) * 8;              // logical col
    const int sw = ((t & 7) ^ (r1 & 7)) * 8;               // swizzled col
    const ushort* Kh0 = Khi + tok0 * D_MODEL + h * HEAD_DIM;
    const ushort* Vt0 = VT + (size_t)(b * NHEAD + h) * HEAD_DIM * SEQ;

    // tile 0 into regs
    int4 pk0 = *(const int4*)(Kh0 + (size_t)r1 * D_MODEL + c1);
    int4 pk1 = *(const int4*)(Kh0 + (size_t)(32 + r1) * D_MODEL + c1);
    int4 pv0 = *(const int4*)(Vt0 + (size_t)r1 * SEQ + c1);
    int4 pv1 = *(const int4*)(Vt0 + (size_t)(32 + r1) * SEQ + c1);

    // tile 0 regs -> buf0
    *(int4*)&lsK[0][r1 * 64 + sw]        = pk0;
    *(int4*)&lsK[0][(32 + r1) * 64 + sw] = pk1;
    *(int4*)&lsV[0][r1 * 64 + sw]        = pv0;
    *(int4*)&lsV[0][(32 + r1) * 64 + sw] = pv1;

    // tile 1 into regs
    pk0 = *(const int4*)(Kh0 + (size_t)(64 + r1) * D_MODEL + c1);
    pk1 = *(const int4*)(Kh0 + (size_t)(96 + r1) * D_MODEL + c1);
    pv0 = *(const int4*)(Vt0 + (size_t)r1 * SEQ + 64 + c1);
    pv1 = *(const int4*)(Vt0 + (size_t)(32 + r1) * SEQ + 64 + c1);
    __syncthreads();

    const float* mrow = mask + (size_t)(q0 + w * 16 + quad * 4) * SEQ;

    // read-side swizzle keys
    const int krd = lane15 & 7;                                   // K/V rows
    const int keyr = (((lane15 >> 2) & 3) << 1) | (lane15 & 1);   // P rows

    int cur = 0;
    for (int kt = 0; kt < SEQ; kt += 64) {
        // 1) regs (tile kt+64) -> buf cur^1   [prev barrier freed it]
        if (kt + 64 < SEQ) {
            *(int4*)&lsK[cur ^ 1][r1 * 64 + sw]        = pk0;
            *(int4*)&lsK[cur ^ 1][(32 + r1) * 64 + sw] = pk1;
            *(int4*)&lsV[cur ^ 1][r1 * 64 + sw]        = pv0;
            *(int4*)&lsV[cur ^ 1][(32 + r1) * 64 + sw] = pv1;
        }

        // 2) mask for THIS tile (issued before K/V so a mask-wait never
        //    drains the younger K/V prefetch loads)
        float mv[4][4];
        #pragma unroll
        for (int nt = 0; nt < 4; nt++)
            #pragma unroll
            for (int rr = 0; rr < 4; rr++)
                mv[nt][rr] = mrow[(size_t)rr * SEQ + kt + nt * 16 + lane15];

        // 3) global prefetch tile kt+128 (wrap -> harmless reload of tile 0)
        const int ktn = (kt + 128 < SEQ) ? kt + 128 : 0;
        pk0 = *(const int4*)(Kh0 + (size_t)(ktn + r1) * D_MODEL + c1);
        pk1 = *(const int4*)(Kh0 + (size_t)(ktn + 32 + r1) * D_MODEL + c1);
        pv0 = *(const int4*)(Vt0 + (size_t)r1 * SEQ + ktn + c1);
        pv1 = *(const int4*)(Vt0 + (size_t)(32 + r1) * SEQ + ktn + c1);

        // 4) S = (Q/8) K^T  (qh + ql) x k   from buf cur
        ffrag s[4];
        #pragma unroll
        for (int nt = 0; nt < 4; nt++) {
            ffrag a = (ffrag){0.f, 0.f, 0.f, 0.f};
            #pragma unroll
            for (int ks = 0; ks < 2; ks++) {
                const bfrag kf = *(const bfrag*)&lsK[cur][(nt * 16 + lane15) * 64 +
                                                          ((ks * 4 + quad) ^ krd) * 8];
                a = __builtin_amdgcn_mfma_f32_16x16x32_bf16(qh[ks], kf, a, 0, 0, 0);
                a = __builtin_amdgcn_mfma_f32_16x16x32_bf16(ql[ks], kf, a, 0, 0, 0);
            }
            s[nt] = a;
        }

        // 5) streaming softmax: exp, per-lane l partials, P^T -> swizzled LDS
        #pragma unroll
        for (int nt = 0; nt < 4; nt++) {
            #pragma unroll
            for (int rr = 0; rr < 4; rr++) {
                const float e = __expf(s[nt][rr] + mv[nt][rr]);
                l_i[rr] += e;
                const int prow = w * 16 + quad * 4 + rr;
                const int pchk = (2 * nt + (lane15 >> 3)) ^ ((quad << 1) | (rr & 1));
                lsP[prow * 64 + pchk * 8 + (lane15 & 7)] = f2bf(e);
            }
        }

        // 6) O += P V  (P rows are wave-private: no barrier)
        #pragma unroll
        for (int ks = 0; ks < 2; ks++) {
            const bfrag pf = *(const bfrag*)&lsP[(w * 16 + lane15) * 64 +
                                                 ((ks * 4 + quad) ^ keyr) * 8];
            #pragma unroll
            for (int nt = 0; nt < 4; nt++) {
                const bfrag vf = *(const bfrag*)&lsV[cur][(nt * 16 + lane15) * 64 +
                                                          ((ks * 4 + quad) ^ krd) * 8];
                of[nt] = __builtin_amdgcn_mfma_f32_16x16x32_bf16(pf, vf, of[nt], 0, 0, 0);
            }
        }

        // 7) single barrier: buf cur^1 writes done for next iter; buf cur
        //    reads done so iter+1 may overwrite it
        __syncthreads();
        cur ^= 1;
    }

    float inv[4];
    #pragma unroll
    for (int rr = 0; rr < 4; rr++) {
        float v = l_i[rr];
        #pragma unroll
        for (int off = 1; off < 16; off <<= 1) v += __shfl_xor(v, off);
        inv[rr] = 1.0f / v;
    }
    #pragma unroll
    for (int nt = 0; nt < 4; nt++)
        #pragma unroll
        for (int rr = 0; rr < 4; rr++)
            out[(tok0 + q0 + w * 16 + quad * 4 + rr) * D_MODEL + h * HEAD_DIM +
                nt * 16 + lane15] = of[nt][rr] * inv[rr];
}

// ---------------------------------------------------------------------------
extern "C" void kernel_launch(void* const* d_in, const int* in_sizes, int n_in,
                              void* d_out, int out_size, void* d_ws, size_t ws_size,
                              hipStream_t stream)
{
    const float* data     = (const float*)d_in[0];
    const float* temporal = (const float*)d_in[1];
    const float* mask     = (const float*)d_in[2];
    const float* Wq = (const float*)d_in[3];
    const float* bq = (const float*)d_in[4];
    const float* Wk = (const float*)d_in[5];
    const float* bk = (const float*)d_in[6];
    const float* Wv = (const float*)d_in[7];
    const float* bv = (const float*)d_in[8];
    float* out = (float*)d_out;

    char* ws = (char*)d_ws;
    const size_t MB = 1024 * 1024;
    ushort* Ahi  = (ushort*)(ws + 0 * MB);
    ushort* Alo  = (ushort*)(ws + 8 * MB);
    ushort* WThi = (ushort*)(ws + 16 * MB);   // 6 MB (3x1024x1024 bf16)
    ushort* Qhi  = (ushort*)(ws + 28 * MB);
    ushort* Qlo  = (ushort*)(ws + 36 * MB);
    ushort* Khi  = (ushort*)(ws + 44 * MB);
    ushort* VT   = (ushort*)(ws + 60 * MB);

    split_data<<<dim3(NTOK * D_MODEL / 1024), 256, 0, stream>>>(data, Ahi, Alo);
    split_tr_w<<<dim3(16, 16, 3), 256, 0, stream>>>(Wq, Wk, Wv, WThi);
    gemm_qkv<<<dim3(NTOK / 128, D_MODEL / 128, 3), 256, 0, stream>>>(
        Ahi, Alo, WThi, bq, bk, bv, temporal,
        Qhi, Qlo, Khi, VT);
    attn_mfma<<<dim3(BATCH * NHEAD * SEQ / 64), 256, 0, stream>>>(
        Qhi, Qlo, Khi, VT, mask, out);
}

// Round 5
// 261.915 us; speedup vs baseline: 1.0669x; 1.0033x over previous
//
#include <hip/hip_runtime.h>
#include <hip/hip_bf16.h>

#define D_MODEL 1024
#define NHEAD   16
#define HEAD_DIM 64
#define BATCH   2
#define SEQ     2048
#define NTOK    (BATCH*SEQ)   // 4096

// log2(10000)/64
#define FREQ_LOG2 0.20762050593046015f

typedef short  bfrag __attribute__((ext_vector_type(8)));  // 8 bf16 = 4 VGPR
typedef float  ffrag __attribute__((ext_vector_type(4)));  // C/D frag

__device__ inline ushort f2bf(float x) {
    __hip_bfloat16 h = __float2bfloat16(x);
    return __builtin_bit_cast(ushort, h);
}
__device__ inline float bf2f(ushort u) {
    return __builtin_bit_cast(float, (uint)u << 16);
}
__device__ inline void split_bf(float x, ushort& hi, ushort& lo) {
    __hip_bfloat16 h = __float2bfloat16(x);
    hi = __builtin_bit_cast(ushort, h);
    lo = f2bf(x - __bfloat162float(h));
}

// async global->LDS DMA, 16B per lane (lds dest = uniform base + lane*16)
__device__ inline void gload16(const ushort* g, ushort* l) {
    __builtin_amdgcn_global_load_lds(
        (const __attribute__((address_space(1))) void*)g,
        (__attribute__((address_space(3))) void*)l, 16, 0, 0);
}

// ---------------------------------------------------------------------------
// Pre-pass 1: split data -> Ahi, Alo  (bf16 hi/lo), [4096][1024]
// ---------------------------------------------------------------------------
__global__ __launch_bounds__(256)
void split_data(const float* __restrict__ x, ushort* __restrict__ hi,
                ushort* __restrict__ lo)
{
    const int i4 = (blockIdx.x * 256 + threadIdx.x) * 4;
    const float4 v = *(const float4*)(x + i4);
    ushort4 h, l;
    split_bf(v.x, h.x, l.x); split_bf(v.y, h.y, l.y);
    split_bf(v.z, h.z, l.z); split_bf(v.w, h.w, l.w);
    *(ushort4*)(hi + i4) = h;
    *(ushort4*)(lo + i4) = l;
}

// ---------------------------------------------------------------------------
// Pre-pass 1b: mask fp32 -> bf16 (halves mask cache/HBM traffic in attn)
// ---------------------------------------------------------------------------
__global__ __launch_bounds__(256)
void mask_bf(const float* __restrict__ m, ushort* __restrict__ o)
{
    const int i4 = (blockIdx.x * 256 + threadIdx.x) * 4;
    const float4 v = *(const float4*)(m + i4);
    ushort4 h;
    h.x = f2bf(v.x); h.y = f2bf(v.y); h.z = f2bf(v.z); h.w = f2bf(v.w);
    *(ushort4*)(o + i4) = h;
}

// ---------------------------------------------------------------------------
// Pre-pass 2: W[k][n] -> WT[n][k], plain bf16.  grid (16,16,3)
// ---------------------------------------------------------------------------
__global__ __launch_bounds__(256)
void split_tr_w(const float* __restrict__ Wq, const float* __restrict__ Wk,
                const float* __restrict__ Wv, ushort* __restrict__ hi)
{
    const int z = blockIdx.z;
    const float* W = (z == 0) ? Wq : (z == 1) ? Wk : Wv;
    ushort* thi = hi + (size_t)z * D_MODEL * D_MODEL;

    __shared__ float T[64][65];
    const int t  = threadIdx.x;
    const int k0 = blockIdx.x * 64, n0 = blockIdx.y * 64;

    #pragma unroll
    for (int i = 0; i < 4; i++) {
        const int f = i * 256 + t, r = f >> 4, c = (f & 15) * 4;
        const float4 v = *(const float4*)(W + (size_t)(k0 + r) * D_MODEL + n0 + c);
        T[r][c] = v.x; T[r][c + 1] = v.y; T[r][c + 2] = v.z; T[r][c + 3] = v.w;
    }
    __syncthreads();
    #pragma unroll
    for (int i = 0; i < 4; i++) {
        const int f = i * 256 + t, nr = f >> 4, kc = (f & 15) * 4;
        ushort4 h;
        h.x = f2bf(T[kc + 0][nr]);
        h.y = f2bf(T[kc + 1][nr]);
        h.z = f2bf(T[kc + 2][nr]);
        h.w = f2bf(T[kc + 3][nr]);
        const size_t o = (size_t)(n0 + nr) * D_MODEL + k0 + kc;
        *(ushort4*)(thi + o) = h;
    }
}

// ---------------------------------------------------------------------------
// Kernel 3: bf16x2 GEMM 128x128xBK32 + bias + RoPE epilogue.
// global_load_lds width-16 into linear double-buffered LDS, 2-phase prefetch,
// ONE barrier per K-step.  LDS layout is chunk-XOR swizzled (rule #21):
//   physical 16B-chunk = logical chunk ^ ((row>>1)&3)
// applied identically on the DMA *source* address (per-lane) and the
// fragment *read* address -> ds_read_b128 is 2-way (free) instead of 8-way.
// z=0 -> Q hi/lo (pre-scaled 1/8); z=1 -> K hi only; z=2 -> VT bf16.
// ---------------------------------------------------------------------------
#define BK 32   // K-step; one LDS row = 32 bf16 = 64B = 4 chunks of 16B

union GemmSM {
    ushort st[2][3][128 * BK];   // [buf][ahi,alo,bhi][row*BK+col]  = 48 KB
    float  c[64 * 132];          // epilogue scratch (33.8 KB)
};

__global__ __launch_bounds__(256, 3)
void gemm_qkv(const ushort* __restrict__ Ahi, const ushort* __restrict__ Alo,
              const ushort* __restrict__ WThi,
              const float* __restrict__ bq, const float* __restrict__ bk,
              const float* __restrict__ bv, const float* __restrict__ temporal,
              ushort* __restrict__ Qhi, ushort* __restrict__ Qlo,
              ushort* __restrict__ Khi,
              ushort* __restrict__ VT)
{
    __shared__ GemmSM sm;
    const int z  = blockIdx.z;
    const int m0 = blockIdx.x * 128;
    const int n0 = blockIdx.y * 128;
    const float* bias = (z == 0) ? bq : (z == 1) ? bk : bv;
    const ushort* Bh = WThi + (size_t)z * D_MODEL * D_MODEL;

    const int t = threadIdx.x;
    const int w = t >> 6, lane = t & 63;
    const int lane15 = lane & 15, quad8 = (lane >> 4) * 8, quad = lane >> 4;
    const int wm = (w >> 1) * 64, wn = (w & 1) * 64;

    ffrag acc[4][4];
    #pragma unroll
    for (int i = 0; i < 4; i++)
        #pragma unroll
        for (int j = 0; j < 4; j++) acc[i][j] = (ffrag){0.f, 0.f, 0.f, 0.f};

    // DMA staging: lane i of a 16-row chunk covers row (i>>2); its LDS slot is
    // physical chunk (i&3), so it must FETCH logical chunk (i&3)^((i>>3)&3)
    // (rb is a multiple of 16, so (row>>1)&3 == (i>>3)&3).
    const int wr = w * 32;                                  // wave's 32-row slab
    const int lr = lane >> 2;                               // row within chunk
    const int lc = (((lane & 3) ^ ((lane >> 3) & 3))) * 8;  // swizzled col (elems)

    auto stage = [&](int bsel, int k0) {
        #pragma unroll
        for (int ch = 0; ch < 2; ch++) {
            const int rb = wr + ch * 16;
            const ushort* ga = Ahi + (size_t)(m0 + rb + lr) * D_MODEL + k0 + lc;
            const ushort* gl = Alo + (size_t)(m0 + rb + lr) * D_MODEL + k0 + lc;
            const ushort* gb = Bh  + (size_t)(n0 + rb + lr) * D_MODEL + k0 + lc;
            gload16(ga, &sm.st[bsel][0][rb * BK]);
            gload16(gl, &sm.st[bsel][1][rb * BK]);
            gload16(gb, &sm.st[bsel][2][rb * BK]);
        }
    };

    stage(0, 0);
    __syncthreads();    // drains vmcnt(0): buf0 ready

    // read-side swizzle: logical chunk 'quad' at row (16-aligned + lane15)
    const int rdsw = (quad ^ ((lane15 >> 1) & 3)) * 8;

    int buf = 0;
    for (int k0 = 0; k0 < D_MODEL; k0 += BK) {
        // issue next tile's async loads before computing this one
        if (k0 + BK < D_MODEL) stage(buf ^ 1, k0 + BK);

        bfrag ah[4], al[4];
        #pragma unroll
        for (int mt = 0; mt < 4; mt++) {
            ah[mt] = *(const bfrag*)&sm.st[buf][0][(wm + mt * 16 + lane15) * BK + rdsw];
            al[mt] = *(const bfrag*)&sm.st[buf][1][(wm + mt * 16 + lane15) * BK + rdsw];
        }
        #pragma unroll
        for (int nt = 0; nt < 4; nt++) {
            const bfrag bh = *(const bfrag*)&sm.st[buf][2][(wn + nt * 16 + lane15) * BK + rdsw];
            #pragma unroll
            for (int mt = 0; mt < 4; mt++) {
                ffrag a = acc[mt][nt];
                a = __builtin_amdgcn_mfma_f32_16x16x32_bf16(ah[mt], bh, a, 0, 0, 0);
                a = __builtin_amdgcn_mfma_f32_16x16x32_bf16(al[mt], bh, a, 0, 0, 0);
                acc[mt][nt] = a;
            }
        }
        __syncthreads();   // drains next-tile DMA + orders reads vs overwrite
        buf ^= 1;
    }

    float bn[4];
    #pragma unroll
    for (int nt = 0; nt < 4; nt++) bn[nt] = bias[n0 + wn + nt * 16 + lane15];

    const int CST = (z == 2) ? 129 : 132;

    #pragma unroll
    for (int p = 0; p < 2; p++) {
        if (p) __syncthreads();
        if ((w >> 1) == p) {
            #pragma unroll
            for (int mt = 0; mt < 4; mt++)
                #pragma unroll
                for (int nt = 0; nt < 4; nt++)
                    #pragma unroll
                    for (int rr = 0; rr < 4; rr++)
                        sm.c[(mt * 16 + quad * 4 + rr) * CST + wn + nt * 16 + lane15] =
                            acc[mt][nt][rr] + bn[nt];
        }
        __syncthreads();

        if (z < 2) {
            ushort* ohi = (z == 0) ? Qhi : Khi;
            const float sc = (z == 0) ? 0.125f : 1.0f;
            #pragma unroll
            for (int i = 0; i < 8; i++) {
                const int f = i * 256 + t, r = f >> 5, c4 = (f & 31) * 4;
                float4 v = *(float4*)&sm.c[r * 132 + c4];
                const int m = m0 + p * 64 + r;
                const float tv = temporal[m];
                const float fr0 = exp2f(-(float)(c4 & 63) * FREQ_LOG2);
                const float fr1 = exp2f(-(float)((c4 + 2) & 63) * FREQ_LOG2);
                float s0, c0, s1, c1v;
                __sincosf(tv * fr0, &s0, &c0);
                __sincosf(tv * fr1, &s1, &c1v);
                const float y0 = (v.x * c0 - v.y * s0) * sc;
                const float y1 = (v.y * c0 + v.x * s0) * sc;
                const float y2 = (v.z * c1v - v.w * s1) * sc;
                const float y3 = (v.w * c1v + v.z * s1) * sc;
                ushort4 h, l;
                split_bf(y0, h.x, l.x); split_bf(y1, h.y, l.y);
                split_bf(y2, h.z, l.z); split_bf(y3, h.w, l.w);
                const size_t o = (size_t)m * D_MODEL + n0 + c4;
                *(ushort4*)(ohi + o) = h;
                if (z == 0) *(ushort4*)(Qlo + o) = l;   // K needs no lo
            }
        } else {
            const int bb = m0 >> 11;
            #pragma unroll
            for (int i = 0; i < 4; i++) {
                const int cid = i * 256 + t, col = cid >> 3, tg = (cid & 7) * 8;
                ushort u8[8];
                #pragma unroll
                for (int j = 0; j < 8; j++) u8[j] = f2bf(sm.c[(tg + j) * 129 + col]);
                const int ncol = n0 + col, hh = ncol >> 6, d = ncol & 63;
                const size_t dst = ((size_t)(bb * NHEAD + hh) * HEAD_DIM + d) * SEQ +
                                   (m0 & (SEQ - 1)) + p * 64 + tg;
                *(int4*)(VT + dst) = *(int4*)u8;
            }
        }
    }
}

// ---------------------------------------------------------------------------
// Kernel 4: MFMA flash attention, streaming softmax.
// R5: QBLK=128 per block (each wave owns 2 16-row q-subtiles).  kf/vf LDS
// fragment reads are shared across both subtiles (2x MFMA per LDS read),
// K/V global+LDS staging per q-row halves, barrier count halves.  Grid 512
// = 2 blocks/CU; latency hiding via 2-subtile ILP.  Mask is bf16.
// K/V double-buffered flat [64][64] rows, XOR chunk swizzle (rule #21):
//   phys 16B-chunk = logical chunk ^ (row & 7), both write and read side.
// P is [128][64] with the same per-16-row involution as R4.
// LDS = 2*8K(K) + 2*8K(V) + 16K(P) = 48 KB.
// ---------------------------------------------------------------------------
__global__ __launch_bounds__(256, 2)
void attn_mfma(const ushort* __restrict__ Qhi, const ushort* __restrict__ Qlo,
               const ushort* __restrict__ Khi,
               const ushort* __restrict__ VT,  const ushort* __restrict__ maskbf,
               float* __restrict__ out)
{
    __shared__ ushort lsK[2][64 * 64], lsV[2][64 * 64], lsP[128 * 64];

    // XCD-L2 swizzle: blocks sharing one (b,h) K/V slab land on one XCD.
    // bid bits: [c:7..8][q:3..6][x:0..2];  bh = x*4+c, qb = q  (bijective).
    const int bid  = blockIdx.x;
    const int bh   = (bid & 7) * 4 + (bid >> 7);
    const int qb   = (bid >> 3) & 15;
    const int b    = bh >> 4, h = bh & 15;
    const int q0   = qb * 128;

    const int t = threadIdx.x, w = t >> 6, lane = t & 63;
    const int lane15 = lane & 15, quad = lane >> 4;
    const size_t tok0 = (size_t)b * SEQ;

    // loop-invariant Q fragments (A-layout), 2 subtiles per wave
    bfrag qh[2][2], ql[2][2];
    #pragma unroll
    for (int su = 0; su < 2; su++) {
        const size_t qrow = (tok0 + q0 + w * 32 + su * 16 + lane15) * D_MODEL +
                            h * HEAD_DIM;
        #pragma unroll
        for (int ks = 0; ks < 2; ks++) {
            qh[su][ks] = *(const bfrag*)(Qhi + qrow + ks * 32 + quad * 8);
            ql[su][ks] = *(const bfrag*)(Qlo + qrow + ks * 32 + quad * 8);
        }
    }

    ffrag of[2][4];
    float l_i[2][4];
    #pragma unroll
    for (int su = 0; su < 2; su++)
        #pragma unroll
        for (int nt = 0; nt < 4; nt++) {
            of[su][nt] = (ffrag){0.f, 0.f, 0.f, 0.f};
            l_i[su][nt] = 0.f;
        }

    // staging: 2 chunks/thread per array (rows 0..31 and 32..63); the
    // write-side swizzle key (row&7) is identical for r1 and r1+32.
    const int r1 = t >> 3,  c1 = (t & 7) * 8;              // logical col
    const int sw = ((t & 7) ^ (r1 & 7)) * 8;               // swizzled col
    const ushort* Kh0 = Khi + tok0 * D_MODEL + h * HEAD_DIM;
    const ushort* Vt0 = VT + (size_t)(b * NHEAD + h) * HEAD_DIM * SEQ;

    // tile 0 into regs
    int4 pk0 = *(const int4*)(Kh0 + (size_t)r1 * D_MODEL + c1);
    int4 pk1 = *(const int4*)(Kh0 + (size_t)(32 + r1) * D_MODEL + c1);
    int4 pv0 = *(const int4*)(Vt0 + (size_t)r1 * SEQ + c1);
    int4 pv1 = *(const int4*)(Vt0 + (size_t)(32 + r1) * SEQ + c1);

    // tile 0 regs -> buf0
    *(int4*)&lsK[0][r1 * 64 + sw]        = pk0;
    *(int4*)&lsK[0][(32 + r1) * 64 + sw] = pk1;
    *(int4*)&lsV[0][r1 * 64 + sw]        = pv0;
    *(int4*)&lsV[0][(32 + r1) * 64 + sw] = pv1;

    // tile 1 into regs
    pk0 = *(const int4*)(Kh0 + (size_t)(64 + r1) * D_MODEL + c1);
    pk1 = *(const int4*)(Kh0 + (size_t)(96 + r1) * D_MODEL + c1);
    pv0 = *(const int4*)(Vt0 + (size_t)r1 * SEQ + 64 + c1);
    pv1 = *(const int4*)(Vt0 + (size_t)(32 + r1) * SEQ + 64 + c1);
    __syncthreads();

    const ushort* mrow0 = maskbf + (size_t)(q0 + w * 32 + quad * 4) * SEQ;
    const ushort* mrow1 = maskbf + (size_t)(q0 + w * 32 + 16 + quad * 4) * SEQ;

    // read-side swizzle keys
    const int krd  = lane15 & 7;                                  // K/V rows
    const int keyr = (((lane15 >> 2) & 3) << 1) | (lane15 & 1);   // P rows

    int cur = 0;
    for (int kt = 0; kt < SEQ; kt += 64) {
        // 1) regs (tile kt+64) -> buf cur^1   [prev barrier freed it]
        if (kt + 64 < SEQ) {
            *(int4*)&lsK[cur ^ 1][r1 * 64 + sw]        = pk0;
            *(int4*)&lsK[cur ^ 1][(32 + r1) * 64 + sw] = pk1;
            *(int4*)&lsV[cur ^ 1][r1 * 64 + sw]        = pv0;
            *(int4*)&lsV[cur ^ 1][(32 + r1) * 64 + sw] = pv1;
        }

        // 2) mask (bf16) for THIS tile
        float mv0[4][4], mv1[4][4];
        #pragma unroll
        for (int nt = 0; nt < 4; nt++)
            #pragma unroll
            for (int rr = 0; rr < 4; rr++) {
                mv0[nt][rr] = bf2f(mrow0[(size_t)rr * SEQ + kt + nt * 16 + lane15]);
                mv1[nt][rr] = bf2f(mrow1[(size_t)rr * SEQ + kt + nt * 16 + lane15]);
            }

        // 3) global prefetch tile kt+128 (wrap -> harmless reload of tile 0)
        const int ktn = (kt + 128 < SEQ) ? kt + 128 : 0;
        pk0 = *(const int4*)(Kh0 + (size_t)(ktn + r1) * D_MODEL + c1);
        pk1 = *(const int4*)(Kh0 + (size_t)(ktn + 32 + r1) * D_MODEL + c1);
        pv0 = *(const int4*)(Vt0 + (size_t)r1 * SEQ + ktn + c1);
        pv1 = *(const int4*)(Vt0 + (size_t)(32 + r1) * SEQ + ktn + c1);

        // 4) S = (Q/8) K^T for both subtiles; kf read ONCE per nt
        ffrag s0[4], s1[4];
        #pragma unroll
        for (int nt = 0; nt < 4; nt++) {
            const bfrag kf0 = *(const bfrag*)&lsK[cur][(nt * 16 + lane15) * 64 +
                                                       ((0 + quad) ^ krd) * 8];
            const bfrag kf1 = *(const bfrag*)&lsK[cur][(nt * 16 + lane15) * 64 +
                                                       ((4 + quad) ^ krd) * 8];
            ffrag a0 = (ffrag){0.f, 0.f, 0.f, 0.f};
            ffrag a1 = (ffrag){0.f, 0.f, 0.f, 0.f};
            a0 = __builtin_amdgcn_mfma_f32_16x16x32_bf16(qh[0][0], kf0, a0, 0, 0, 0);
            a0 = __builtin_amdgcn_mfma_f32_16x16x32_bf16(ql[0][0], kf0, a0, 0, 0, 0);
            a0 = __builtin_amdgcn_mfma_f32_16x16x32_bf16(qh[0][1], kf1, a0, 0, 0, 0);
            a0 = __builtin_amdgcn_mfma_f32_16x16x32_bf16(ql[0][1], kf1, a0, 0, 0, 0);
            a1 = __builtin_amdgcn_mfma_f32_16x16x32_bf16(qh[1][0], kf0, a1, 0, 0, 0);
            a1 = __builtin_amdgcn_mfma_f32_16x16x32_bf16(ql[1][0], kf0, a1, 0, 0, 0);
            a1 = __builtin_amdgcn_mfma_f32_16x16x32_bf16(qh[1][1], kf1, a1, 0, 0, 0);
            a1 = __builtin_amdgcn_mfma_f32_16x16x32_bf16(ql[1][1], kf1, a1, 0, 0, 0);
            s0[nt] = a0;
            s1[nt] = a1;
        }

        // 5) streaming softmax: exp, per-lane l partials, P^T -> swizzled LDS
        #pragma unroll
        for (int nt = 0; nt < 4; nt++)
            #pragma unroll
            for (int rr = 0; rr < 4; rr++) {
                const int pchk = (2 * nt + (lane15 >> 3)) ^ ((quad << 1) | (rr & 1));
                const float e0 = __expf(s0[nt][rr] + mv0[nt][rr]);
                l_i[0][rr] += e0;
                lsP[(w * 32 + quad * 4 + rr) * 64 + pchk * 8 + (lane15 & 7)] = f2bf(e0);
                const float e1 = __expf(s1[nt][rr] + mv1[nt][rr]);
                l_i[1][rr] += e1;
                lsP[(w * 32 + 16 + quad * 4 + rr) * 64 + pchk * 8 + (lane15 & 7)] = f2bf(e1);
            }

        // 6) O += P V  (P rows are wave-private: no barrier); vf read ONCE
        #pragma unroll
        for (int ks = 0; ks < 2; ks++) {
            const bfrag pf0 = *(const bfrag*)&lsP[(w * 32 + lane15) * 64 +
                                                  ((ks * 4 + quad) ^ keyr) * 8];
            const bfrag pf1 = *(const bfrag*)&lsP[(w * 32 + 16 + lane15) * 64 +
                                                  ((ks * 4 + quad) ^ keyr) * 8];
            #pragma unroll
            for (int nt = 0; nt < 4; nt++) {
                const bfrag vf = *(const bfrag*)&lsV[cur][(nt * 16 + lane15) * 64 +
                                                          ((ks * 4 + quad) ^ krd) * 8];
                of[0][nt] = __builtin_amdgcn_mfma_f32_16x16x32_bf16(pf0, vf, of[0][nt], 0, 0, 0);
                of[1][nt] = __builtin_amdgcn_mfma_f32_16x16x32_bf16(pf1, vf, of[1][nt], 0, 0, 0);
            }
        }

        // 7) single barrier per KV tile
        __syncthreads();
        cur ^= 1;
    }

    #pragma unroll
    for (int su = 0; su < 2; su++) {
        float inv[4];
        #pragma unroll
        for (int rr = 0; rr < 4; rr++) {
            float v = l_i[su][rr];
            #pragma unroll
            for (int off = 1; off < 16; off <<= 1) v += __shfl_xor(v, off);
            inv[rr] = 1.0f / v;
        }
        #pragma unroll
        for (int nt = 0; nt < 4; nt++)
            #pragma unroll
            for (int rr = 0; rr < 4; rr++)
                out[(tok0 + q0 + w * 32 + su * 16 + quad * 4 + rr) * D_MODEL +
                    h * HEAD_DIM + nt * 16 + lane15] = of[su][nt][rr] * inv[rr];
    }
}

// ---------------------------------------------------------------------------
extern "C" void kernel_launch(void* const* d_in, const int* in_sizes, int n_in,
                              void* d_out, int out_size, void* d_ws, size_t ws_size,
                              hipStream_t stream)
{
    const float* data     = (const float*)d_in[0];
    const float* temporal = (const float*)d_in[1];
    const float* mask     = (const float*)d_in[2];
    const float* Wq = (const float*)d_in[3];
    const float* bq = (const float*)d_in[4];
    const float* Wk = (const float*)d_in[5];
    const float* bk = (const float*)d_in[6];
    const float* Wv = (const float*)d_in[7];
    const float* bv = (const float*)d_in[8];
    float* out = (float*)d_out;

    char* ws = (char*)d_ws;
    const size_t MB = 1024 * 1024;
    ushort* Ahi  = (ushort*)(ws + 0 * MB);
    ushort* Alo  = (ushort*)(ws + 8 * MB);
    ushort* WThi = (ushort*)(ws + 16 * MB);   // 6 MB (3x1024x1024 bf16)
    ushort* Qhi  = (ushort*)(ws + 28 * MB);
    ushort* Qlo  = (ushort*)(ws + 36 * MB);
    ushort* Khi  = (ushort*)(ws + 44 * MB);
    ushort* VT   = (ushort*)(ws + 60 * MB);   // 8 MB
    ushort* Mbf  = (ushort*)(ws + 68 * MB);   // 8 MB (2048x2048 bf16)

    split_data<<<dim3(NTOK * D_MODEL / 1024), 256, 0, stream>>>(data, Ahi, Alo);
    mask_bf<<<dim3(SEQ * SEQ / 1024), 256, 0, stream>>>(mask, Mbf);
    split_tr_w<<<dim3(16, 16, 3), 256, 0, stream>>>(Wq, Wk, Wv, WThi);
    gemm_qkv<<<dim3(NTOK / 128, D_MODEL / 128, 3), 256, 0, stream>>>(
        Ahi, Alo, WThi, bq, bk, bv, temporal,
        Qhi, Qlo, Khi, VT);
    attn_mfma<<<dim3(BATCH * NHEAD * SEQ / 128), 256, 0, stream>>>(
        Qhi, Qlo, Khi, VT, Mbf, out);
}

// Round 7
// 258.607 us; speedup vs baseline: 1.0806x; 1.0128x over previous
//
#include <hip/hip_runtime.h>
#include <hip/hip_bf16.h>

#define D_MODEL 1024
#define NHEAD   16
#define HEAD_DIM 64
#define BATCH   2
#define SEQ     2048
#define NTOK    (BATCH*SEQ)   // 4096

// log2(10000)/64
#define FREQ_LOG2 0.20762050593046015f

typedef short  bfrag __attribute__((ext_vector_type(8)));  // 8 bf16 = 4 VGPR
typedef float  ffrag __attribute__((ext_vector_type(4)));  // C/D frag

__device__ inline ushort f2bf(float x) {
    __hip_bfloat16 h = __float2bfloat16(x);
    return __builtin_bit_cast(ushort, h);
}
__device__ inline float bf2f(ushort u) {
    return __builtin_bit_cast(float, (uint)u << 16);
}
__device__ inline void split_bf(float x, ushort& hi, ushort& lo) {
    __hip_bfloat16 h = __float2bfloat16(x);
    hi = __builtin_bit_cast(ushort, h);
    lo = f2bf(x - __bfloat162float(h));
}

// async global->LDS DMA, 16B per lane (lds dest = uniform base + lane*16)
__device__ inline void gload16(const ushort* g, ushort* l) {
    __builtin_amdgcn_global_load_lds(
        (const __attribute__((address_space(1))) void*)g,
        (__attribute__((address_space(3))) void*)l, 16, 0, 0);
}

// ---------------------------------------------------------------------------
// Fused pre-pass (one node instead of three):
//   blocks [0,4096):     data -> Ahi/Alo bf16 hi/lo split
//   blocks [4096,8192):  mask fp32 -> bf16
//   blocks [8192,8960):  W[k][n] -> WT[n][k] bf16 (LDS transpose), 256/z
// ---------------------------------------------------------------------------
__global__ __launch_bounds__(256)
void prep(const float* __restrict__ data, ushort* __restrict__ Ahi,
          ushort* __restrict__ Alo,
          const float* __restrict__ mask, ushort* __restrict__ Mbf,
          const float* __restrict__ Wq, const float* __restrict__ Wk,
          const float* __restrict__ Wv, ushort* __restrict__ WThi)
{
    __shared__ float T[64][65];
    const int bid = blockIdx.x, t = threadIdx.x;

    if (bid < 4096) {                       // split_data
        const int i4 = (bid * 256 + t) * 4;
        const float4 v = *(const float4*)(data + i4);
        ushort4 h, l;
        split_bf(v.x, h.x, l.x); split_bf(v.y, h.y, l.y);
        split_bf(v.z, h.z, l.z); split_bf(v.w, h.w, l.w);
        *(ushort4*)(Ahi + i4) = h;
        *(ushort4*)(Alo + i4) = l;
        return;
    }
    if (bid < 8192) {                       // mask -> bf16
        const int i4 = ((bid - 4096) * 256 + t) * 4;
        const float4 v = *(const float4*)(mask + i4);
        ushort4 h;
        h.x = f2bf(v.x); h.y = f2bf(v.y); h.z = f2bf(v.z); h.w = f2bf(v.w);
        *(ushort4*)(Mbf + i4) = h;
        return;
    }
    // W transpose
    const int id  = bid - 8192;             // 0..767
    const int z   = id >> 8;
    const int rem = id & 255;
    const int k0  = (rem & 15) * 64, n0 = (rem >> 4) * 64;
    const float* W = (z == 0) ? Wq : (z == 1) ? Wk : Wv;
    ushort* thi = WThi + (size_t)z * D_MODEL * D_MODEL;

    #pragma unroll
    for (int i = 0; i < 4; i++) {
        const int f = i * 256 + t, r = f >> 4, c = (f & 15) * 4;
        const float4 v = *(const float4*)(W + (size_t)(k0 + r) * D_MODEL + n0 + c);
        T[r][c] = v.x; T[r][c + 1] = v.y; T[r][c + 2] = v.z; T[r][c + 3] = v.w;
    }
    __syncthreads();
    #pragma unroll
    for (int i = 0; i < 4; i++) {
        const int f = i * 256 + t, nr = f >> 4, kc = (f & 15) * 4;
        ushort4 h;
        h.x = f2bf(T[kc + 0][nr]);
        h.y = f2bf(T[kc + 1][nr]);
        h.z = f2bf(T[kc + 2][nr]);
        h.w = f2bf(T[kc + 3][nr]);
        const size_t o = (size_t)(n0 + nr) * D_MODEL + k0 + kc;
        *(ushort4*)(thi + o) = h;
    }
}

// ---------------------------------------------------------------------------
// Kernel 3: bf16x2 GEMM 128x128xBK32 + bias + RoPE epilogue.
// global_load_lds width-16 into linear double-buffered LDS, 2-phase prefetch,
// ONE barrier per K-step.  Chunk-XOR LDS swizzle on both DMA-source and
// fragment-read side (rule #21).  R6: 1-D grid + XCD swizzle (T1): each XCD
// owns 4 consecutive m-slabs (2 MB of A, L2-resident) across all 24 (n,z)
// tiles -> A re-reads become XCD-L2 hits.
// ---------------------------------------------------------------------------
#define BK 32   // K-step; one LDS row = 32 bf16 = 64B = 4 chunks of 16B

union GemmSM {
    ushort st[2][3][128 * BK];   // [buf][ahi,alo,bhi][row*BK+col]  = 48 KB
    float  c[64 * 132];          // epilogue scratch (33.8 KB)
};

__global__ __launch_bounds__(256, 3)
void gemm_qkv(const ushort* __restrict__ Ahi, const ushort* __restrict__ Alo,
              const ushort* __restrict__ WThi,
              const float* __restrict__ bq, const float* __restrict__ bk,
              const float* __restrict__ bv, const float* __restrict__ temporal,
              ushort* __restrict__ Qhi, ushort* __restrict__ Qlo,
              ushort* __restrict__ Khi,
              ushort* __restrict__ VT)
{
    __shared__ GemmSM sm;
    // XCD swizzle: bidl%8 = XCD slot; XCD x gets m-slabs 4x..4x+3 for all n,z
    const int bidl = blockIdx.x;                 // 0..767
    const int xcd  = bidl & 7, kk = bidl >> 3;   // kk 0..95
    const int m0   = (xcd * 4 + (kk & 3)) * 128;
    const int nz   = kk >> 2;                    // 0..23
    const int n0   = (nz & 7) * 128;
    const int z    = nz >> 3;

    const float* bias = (z == 0) ? bq : (z == 1) ? bk : bv;
    const ushort* Bh = WThi + (size_t)z * D_MODEL * D_MODEL;

    const int t = threadIdx.x;
    const int w = t >> 6, lane = t & 63;
    const int lane15 = lane & 15, quad8 = (lane >> 4) * 8, quad = lane >> 4;
    const int wm = (w >> 1) * 64, wn = (w & 1) * 64;

    ffrag acc[4][4];
    #pragma unroll
    for (int i = 0; i < 4; i++)
        #pragma unroll
        for (int j = 0; j < 4; j++) acc[i][j] = (ffrag){0.f, 0.f, 0.f, 0.f};

    // DMA staging: lane i of a 16-row chunk covers row (i>>2); its LDS slot is
    // physical chunk (i&3), so it must FETCH logical chunk (i&3)^((i>>3)&3).
    const int wr = w * 32;                                  // wave's 32-row slab
    const int lr = lane >> 2;                               // row within chunk
    const int lc = (((lane & 3) ^ ((lane >> 3) & 3))) * 8;  // swizzled col (elems)

    auto stage = [&](int bsel, int k0) {
        #pragma unroll
        for (int ch = 0; ch < 2; ch++) {
            const int rb = wr + ch * 16;
            const ushort* ga = Ahi + (size_t)(m0 + rb + lr) * D_MODEL + k0 + lc;
            const ushort* gl = Alo + (size_t)(m0 + rb + lr) * D_MODEL + k0 + lc;
            const ushort* gb = Bh  + (size_t)(n0 + rb + lr) * D_MODEL + k0 + lc;
            gload16(ga, &sm.st[bsel][0][rb * BK]);
            gload16(gl, &sm.st[bsel][1][rb * BK]);
            gload16(gb, &sm.st[bsel][2][rb * BK]);
        }
    };

    stage(0, 0);
    __syncthreads();    // drains vmcnt(0): buf0 ready

    // read-side swizzle: logical chunk 'quad' at row (16-aligned + lane15)
    const int rdsw = (quad ^ ((lane15 >> 1) & 3)) * 8;

    int buf = 0;
    for (int k0 = 0; k0 < D_MODEL; k0 += BK) {
        // issue next tile's async loads before computing this one
        if (k0 + BK < D_MODEL) stage(buf ^ 1, k0 + BK);

        bfrag ah[4], al[4];
        #pragma unroll
        for (int mt = 0; mt < 4; mt++) {
            ah[mt] = *(const bfrag*)&sm.st[buf][0][(wm + mt * 16 + lane15) * BK + rdsw];
            al[mt] = *(const bfrag*)&sm.st[buf][1][(wm + mt * 16 + lane15) * BK + rdsw];
        }
        #pragma unroll
        for (int nt = 0; nt < 4; nt++) {
            const bfrag bh = *(const bfrag*)&sm.st[buf][2][(wn + nt * 16 + lane15) * BK + rdsw];
            #pragma unroll
            for (int mt = 0; mt < 4; mt++) {
                ffrag a = acc[mt][nt];
                a = __builtin_amdgcn_mfma_f32_16x16x32_bf16(ah[mt], bh, a, 0, 0, 0);
                a = __builtin_amdgcn_mfma_f32_16x16x32_bf16(al[mt], bh, a, 0, 0, 0);
                acc[mt][nt] = a;
            }
        }
        __syncthreads();   // drains next-tile DMA + orders reads vs overwrite
        buf ^= 1;
    }

    float bn[4];
    #pragma unroll
    for (int nt = 0; nt < 4; nt++) bn[nt] = bias[n0 + wn + nt * 16 + lane15];

    const int CST = (z == 2) ? 129 : 132;

    #pragma unroll
    for (int p = 0; p < 2; p++) {
        if (p) __syncthreads();
        if ((w >> 1) == p) {
            #pragma unroll
            for (int mt = 0; mt < 4; mt++)
                #pragma unroll
                for (int nt = 0; nt < 4; nt++)
                    #pragma unroll
                    for (int rr = 0; rr < 4; rr++)
                        sm.c[(mt * 16 + quad * 4 + rr) * CST + wn + nt * 16 + lane15] =
                            acc[mt][nt][rr] + bn[nt];
        }
        __syncthreads();

        if (z < 2) {
            ushort* ohi = (z == 0) ? Qhi : Khi;
            const float sc = (z == 0) ? 0.125f : 1.0f;
            #pragma unroll
            for (int i = 0; i < 8; i++) {
                const int f = i * 256 + t, r = f >> 5, c4 = (f & 31) * 4;
                float4 v = *(float4*)&sm.c[r * 132 + c4];
                const int m = m0 + p * 64 + r;
                const float tv = temporal[m];
                const float fr0 = exp2f(-(float)(c4 & 63) * FREQ_LOG2);
                const float fr1 = exp2f(-(float)((c4 + 2) & 63) * FREQ_LOG2);
                float s0, c0, s1, c1v;
                __sincosf(tv * fr0, &s0, &c0);
                __sincosf(tv * fr1, &s1, &c1v);
                const float y0 = (v.x * c0 - v.y * s0) * sc;
                const float y1 = (v.y * c0 + v.x * s0) * sc;
                const float y2 = (v.z * c1v - v.w * s1) * sc;
                const float y3 = (v.w * c1v + v.z * s1) * sc;
                ushort4 h, l;
                split_bf(y0, h.x, l.x); split_bf(y1, h.y, l.y);
                split_bf(y2, h.z, l.z); split_bf(y3, h.w, l.w);
                const size_t o = (size_t)m * D_MODEL + n0 + c4;
                *(ushort4*)(ohi + o) = h;
                if (z == 0) *(ushort4*)(Qlo + o) = l;   // K needs no lo
            }
        } else {
            const int bb = m0 >> 11;
            #pragma unroll
            for (int i = 0; i < 4; i++) {
                const int cid = i * 256 + t, col = cid >> 3, tg = (cid & 7) * 8;
                ushort u8[8];
                #pragma unroll
                for (int j = 0; j < 8; j++) u8[j] = f2bf(sm.c[(tg + j) * 129 + col]);
                const int ncol = n0 + col, hh = ncol >> 6, d = ncol & 63;
                const size_t dst = ((size_t)(bb * NHEAD + hh) * HEAD_DIM + d) * SEQ +
                                   (m0 & (SEQ - 1)) + p * 64 + tg;
                *(int4*)(VT + dst) = *(int4*)u8;
            }
        }
    }
}

// ---------------------------------------------------------------------------
// Kernel 4: MFMA flash attention, streaming softmax, QBLK=128 (2 q-subtiles
// per wave), double-buffered K/V, ONE barrier per KV tile, XOR chunk swizzle
// on K/V/P (rule #21).  R6: s_setprio(1) around both MFMA clusters (T5 —
// attn blocks are independent, so the CU scheduler has role diversity).
// ---------------------------------------------------------------------------
__global__ __launch_bounds__(256, 2)
void attn_mfma(const ushort* __restrict__ Qhi, const ushort* __restrict__ Qlo,
               const ushort* __restrict__ Khi,
               const ushort* __restrict__ VT,  const ushort* __restrict__ maskbf,
               float* __restrict__ out)
{
    __shared__ ushort lsK[2][64 * 64], lsV[2][64 * 64], lsP[128 * 64];

    const int bid  = blockIdx.x;
    const int bh   = (bid & 7) * 4 + (bid >> 7);
    const int qb   = (bid >> 3) & 15;
    const int b    = bh >> 4, h = bh & 15;
    const int q0   = qb * 128;

    const int t = threadIdx.x, w = t >> 6, lane = t & 63;
    const int lane15 = lane & 15, quad = lane >> 4;
    const size_t tok0 = (size_t)b * SEQ;

    // loop-invariant Q fragments (A-layout), 2 subtiles per wave
    bfrag qh[2][2], ql[2][2];
    #pragma unroll
    for (int su = 0; su < 2; su++) {
        const size_t qrow = (tok0 + q0 + w * 32 + su * 16 + lane15) * D_MODEL +
                            h * HEAD_DIM;
        #pragma unroll
        for (int ks = 0; ks < 2; ks++) {
            qh[su][ks] = *(const bfrag*)(Qhi + qrow + ks * 32 + quad * 8);
            ql[su][ks] = *(const bfrag*)(Qlo + qrow + ks * 32 + quad * 8);
        }
    }

    ffrag of[2][4];
    float l_i[2][4];
    #pragma unroll
    for (int su = 0; su < 2; su++)
        #pragma unroll
        for (int nt = 0; nt < 4; nt++) {
            of[su][nt] = (ffrag){0.f, 0.f, 0.f, 0.f};
            l_i[su][nt] = 0.f;
        }

    const int r1 = t >> 3,  c1 = (t & 7) * 8;              // logical col
    const int sw = ((t & 7) ^ (r1 & 7)) * 8;               // swizzled col
    const ushort* Kh0 = Khi + tok0 * D_MODEL + h * HEAD_DIM;
    const ushort* Vt0 = VT + (size_t)(b * NHEAD + h) * HEAD_DIM * SEQ;

    // tile 0 into regs
    int4 pk0 = *(const int4*)(Kh0 + (size_t)r1 * D_MODEL + c1);
    int4 pk1 = *(const int4*)(Kh0 + (size_t)(32 + r1) * D_MODEL + c1);
    int4 pv0 = *(const int4*)(Vt0 + (size_t)r1 * SEQ + c1);
    int4 pv1 = *(const int4*)(Vt0 + (size_t)(32 + r1) * SEQ + c1);

    // tile 0 regs -> buf0
    *(int4*)&lsK[0][r1 * 64 + sw]        = pk0;
    *(int4*)&lsK[0][(32 + r1) * 64 + sw] = pk1;
    *(int4*)&lsV[0][r1 * 64 + sw]        = pv0;
    *(int4*)&lsV[0][(32 + r1) * 64 + sw] = pv1;

    // tile 1 into regs
    pk0 = *(const int4*)(Kh0 + (size_t)(64 + r1) * D_MODEL + c1);
    pk1 = *(const int4*)(Kh0 + (size_t)(96 + r1) * D_MODEL + c1);
    pv0 = *(const int4*)(Vt0 + (size_t)r1 * SEQ + 64 + c1);
    pv1 = *(const int4*)(Vt0 + (size_t)(32 + r1) * SEQ + 64 + c1);
    __syncthreads();

    const ushort* mrow0 = maskbf + (size_t)(q0 + w * 32 + quad * 4) * SEQ;
    const ushort* mrow1 = maskbf + (size_t)(q0 + w * 32 + 16 + quad * 4) * SEQ;

    const int krd  = lane15 & 7;                                  // K/V rows
    const int keyr = (((lane15 >> 2) & 3) << 1) | (lane15 & 1);   // P rows

    int cur = 0;
    for (int kt = 0; kt < SEQ; kt += 64) {
        // 1) regs (tile kt+64) -> buf cur^1
        if (kt + 64 < SEQ) {
            *(int4*)&lsK[cur ^ 1][r1 * 64 + sw]        = pk0;
            *(int4*)&lsK[cur ^ 1][(32 + r1) * 64 + sw] = pk1;
            *(int4*)&lsV[cur ^ 1][r1 * 64 + sw]        = pv0;
            *(int4*)&lsV[cur ^ 1][(32 + r1) * 64 + sw] = pv1;
        }

        // 2) mask (bf16) for THIS tile
        float mv0[4][4], mv1[4][4];
        #pragma unroll
        for (int nt = 0; nt < 4; nt++)
            #pragma unroll
            for (int rr = 0; rr < 4; rr++) {
                mv0[nt][rr] = bf2f(mrow0[(size_t)rr * SEQ + kt + nt * 16 + lane15]);
                mv1[nt][rr] = bf2f(mrow1[(size_t)rr * SEQ + kt + nt * 16 + lane15]);
            }

        // 3) global prefetch tile kt+128
        const int ktn = (kt + 128 < SEQ) ? kt + 128 : 0;
        pk0 = *(const int4*)(Kh0 + (size_t)(ktn + r1) * D_MODEL + c1);
        pk1 = *(const int4*)(Kh0 + (size_t)(ktn + 32 + r1) * D_MODEL + c1);
        pv0 = *(const int4*)(Vt0 + (size_t)r1 * SEQ + ktn + c1);
        pv1 = *(const int4*)(Vt0 + (size_t)(32 + r1) * SEQ + ktn + c1);

        // 4) S = (Q/8) K^T for both subtiles; kf read ONCE per nt
        ffrag s0[4], s1[4];
        __builtin_amdgcn_s_setprio(1);
        #pragma unroll
        for (int nt = 0; nt < 4; nt++) {
            const bfrag kf0 = *(const bfrag*)&lsK[cur][(nt * 16 + lane15) * 64 +
                                                       ((0 + quad) ^ krd) * 8];
            const bfrag kf1 = *(const bfrag*)&lsK[cur][(nt * 16 + lane15) * 64 +
                                                       ((4 + quad) ^ krd) * 8];
            ffrag a0 = (ffrag){0.f, 0.f, 0.f, 0.f};
            ffrag a1 = (ffrag){0.f, 0.f, 0.f, 0.f};
            a0 = __builtin_amdgcn_mfma_f32_16x16x32_bf16(qh[0][0], kf0, a0, 0, 0, 0);
            a0 = __builtin_amdgcn_mfma_f32_16x16x32_bf16(ql[0][0], kf0, a0, 0, 0, 0);
            a0 = __builtin_amdgcn_mfma_f32_16x16x32_bf16(qh[0][1], kf1, a0, 0, 0, 0);
            a0 = __builtin_amdgcn_mfma_f32_16x16x32_bf16(ql[0][1], kf1, a0, 0, 0, 0);
            a1 = __builtin_amdgcn_mfma_f32_16x16x32_bf16(qh[1][0], kf0, a1, 0, 0, 0);
            a1 = __builtin_amdgcn_mfma_f32_16x16x32_bf16(ql[1][0], kf0, a1, 0, 0, 0);
            a1 = __builtin_amdgcn_mfma_f32_16x16x32_bf16(qh[1][1], kf1, a1, 0, 0, 0);
            a1 = __builtin_amdgcn_mfma_f32_16x16x32_bf16(ql[1][1], kf1, a1, 0, 0, 0);
            s0[nt] = a0;
            s1[nt] = a1;
        }
        __builtin_amdgcn_s_setprio(0);

        // 5) streaming softmax: exp, per-lane l partials, P^T -> swizzled LDS
        #pragma unroll
        for (int nt = 0; nt < 4; nt++)
            #pragma unroll
            for (int rr = 0; rr < 4; rr++) {
                const int pchk = (2 * nt + (lane15 >> 3)) ^ ((quad << 1) | (rr & 1));
                const float e0 = __expf(s0[nt][rr] + mv0[nt][rr]);
                l_i[0][rr] += e0;
                lsP[(w * 32 + quad * 4 + rr) * 64 + pchk * 8 + (lane15 & 7)] = f2bf(e0);
                const float e1 = __expf(s1[nt][rr] + mv1[nt][rr]);
                l_i[1][rr] += e1;
                lsP[(w * 32 + 16 + quad * 4 + rr) * 64 + pchk * 8 + (lane15 & 7)] = f2bf(e1);
            }

        // 6) O += P V  (P rows are wave-private: no barrier); vf read ONCE
        __builtin_amdgcn_s_setprio(1);
        #pragma unroll
        for (int ks = 0; ks < 2; ks++) {
            const bfrag pf0 = *(const bfrag*)&lsP[(w * 32 + lane15) * 64 +
                                                  ((ks * 4 + quad) ^ keyr) * 8];
            const bfrag pf1 = *(const bfrag*)&lsP[(w * 32 + 16 + lane15) * 64 +
                                                  ((ks * 4 + quad) ^ keyr) * 8];
            #pragma unroll
            for (int nt = 0; nt < 4; nt++) {
                const bfrag vf = *(const bfrag*)&lsV[cur][(nt * 16 + lane15) * 64 +
                                                          ((ks * 4 + quad) ^ krd) * 8];
                of[0][nt] = __builtin_amdgcn_mfma_f32_16x16x32_bf16(pf0, vf, of[0][nt], 0, 0, 0);
                of[1][nt] = __builtin_amdgcn_mfma_f32_16x16x32_bf16(pf1, vf, of[1][nt], 0, 0, 0);
            }
        }
        __builtin_amdgcn_s_setprio(0);

        // 7) single barrier per KV tile
        __syncthreads();
        cur ^= 1;
    }

    #pragma unroll
    for (int su = 0; su < 2; su++) {
        float inv[4];
        #pragma unroll
        for (int rr = 0; rr < 4; rr++) {
            float v = l_i[su][rr];
            #pragma unroll
            for (int off = 1; off < 16; off <<= 1) v += __shfl_xor(v, off);
            inv[rr] = 1.0f / v;
        }
        #pragma unroll
        for (int nt = 0; nt < 4; nt++)
            #pragma unroll
            for (int rr = 0; rr < 4; rr++)
                out[(tok0 + q0 + w * 32 + su * 16 + quad * 4 + rr) * D_MODEL +
                    h * HEAD_DIM + nt * 16 + lane15] = of[su][nt][rr] * inv[rr];
    }
}

// ---------------------------------------------------------------------------
extern "C" void kernel_launch(void* const* d_in, const int* in_sizes, int n_in,
                              void* d_out, int out_size, void* d_ws, size_t ws_size,
                              hipStream_t stream)
{
    const float* data     = (const float*)d_in[0];
    const float* temporal = (const float*)d_in[1];
    const float* mask     = (const float*)d_in[2];
    const float* Wq = (const float*)d_in[3];
    const float* bq = (const float*)d_in[4];
    const float* Wk = (const float*)d_in[5];
    const float* bk = (const float*)d_in[6];
    const float* Wv = (const float*)d_in[7];
    const float* bv = (const float*)d_in[8];
    float* out = (float*)d_out;

    char* ws = (char*)d_ws;
    const size_t MB = 1024 * 1024;
    ushort* Ahi  = (ushort*)(ws + 0 * MB);
    ushort* Alo  = (ushort*)(ws + 8 * MB);
    ushort* WThi = (ushort*)(ws + 16 * MB);   // 6 MB (3x1024x1024 bf16)
    ushort* Qhi  = (ushort*)(ws + 28 * MB);
    ushort* Qlo  = (ushort*)(ws + 36 * MB);
    ushort* Khi  = (ushort*)(ws + 44 * MB);
    ushort* VT   = (ushort*)(ws + 60 * MB);   // 8 MB
    ushort* Mbf  = (ushort*)(ws + 68 * MB);   // 8 MB (2048x2048 bf16)

    prep<<<dim3(8960), 256, 0, stream>>>(data, Ahi, Alo, mask, Mbf,
                                         Wq, Wk, Wv, WThi);
    gemm_qkv<<<dim3(768), 256, 0, stream>>>(
        Ahi, Alo, WThi, bq, bk, bv, temporal,
        Qhi, Qlo, Khi, VT);
    attn_mfma<<<dim3(BATCH * NHEAD * SEQ / 128), 256, 0, stream>>>(
        Qhi, Qlo, Khi, VT, Mbf, out);
}

// Round 8
// 251.272 us; speedup vs baseline: 1.1121x; 1.0292x over previous
//
#include <hip/hip_runtime.h>
#include <hip/hip_bf16.h>

#define D_MODEL 1024
#define NHEAD   16
#define HEAD_DIM 64
#define BATCH   2
#define SEQ     2048
#define NTOK    (BATCH*SEQ)   // 4096

// log2(10000)/64
#define FREQ_LOG2 0.20762050593046015f

typedef short  bfrag __attribute__((ext_vector_type(8)));  // 8 bf16 = 4 VGPR
typedef float  ffrag __attribute__((ext_vector_type(4)));  // C/D frag

__device__ inline ushort f2bf(float x) {
    __hip_bfloat16 h = __float2bfloat16(x);
    return __builtin_bit_cast(ushort, h);
}
__device__ inline float bf2f(ushort u) {
    return __builtin_bit_cast(float, (uint)u << 16);
}
__device__ inline void split_bf(float x, ushort& hi, ushort& lo) {
    __hip_bfloat16 h = __float2bfloat16(x);
    hi = __builtin_bit_cast(ushort, h);
    lo = f2bf(x - __bfloat162float(h));
}

// async global->LDS DMA, 16B per lane (lds dest = uniform base + lane*16)
__device__ inline void gload16(const ushort* g, ushort* l) {
    __builtin_amdgcn_global_load_lds(
        (const __attribute__((address_space(1))) void*)g,
        (__attribute__((address_space(3))) void*)l, 16, 0, 0);
}

// ---------------------------------------------------------------------------
// Fused pre-pass:
//   blocks [0,4096):     data -> Ahi/Alo bf16 hi/lo split
//   blocks [4096,8192):  mask fp32 -> bf16  + per-block nonzero flag MZnz
//   blocks [8192,8960):  W[k][n] -> WT[n][k] bf16 (LDS transpose)
// ---------------------------------------------------------------------------
__global__ __launch_bounds__(256)
void prep(const float* __restrict__ data, ushort* __restrict__ Ahi,
          ushort* __restrict__ Alo,
          const float* __restrict__ mask, ushort* __restrict__ Mbf,
          int* __restrict__ MZnz,
          const float* __restrict__ Wq, const float* __restrict__ Wk,
          const float* __restrict__ Wv, ushort* __restrict__ WThi)
{
    __shared__ float T[64][65];
    __shared__ int bnz;
    const int bid = blockIdx.x, t = threadIdx.x;

    if (bid < 4096) {                       // split_data
        const int i4 = (bid * 256 + t) * 4;
        const float4 v = *(const float4*)(data + i4);
        ushort4 h, l;
        split_bf(v.x, h.x, l.x); split_bf(v.y, h.y, l.y);
        split_bf(v.z, h.z, l.z); split_bf(v.w, h.w, l.w);
        *(ushort4*)(Ahi + i4) = h;
        *(ushort4*)(Alo + i4) = l;
        return;
    }
    if (bid < 8192) {                       // mask -> bf16 + nonzero flag
        const int mi = bid - 4096;
        const int i4 = (mi * 256 + t) * 4;
        const float4 v = *(const float4*)(mask + i4);
        ushort4 h;
        h.x = f2bf(v.x); h.y = f2bf(v.y); h.z = f2bf(v.z); h.w = f2bf(v.w);
        *(ushort4*)(Mbf + i4) = h;
        const int nz = (v.x != 0.f) || (v.y != 0.f) || (v.z != 0.f) || (v.w != 0.f);
        if (t == 0) bnz = 0;
        __syncthreads();
        if (nz) atomicOr(&bnz, 1);
        __syncthreads();
        if (t == 0) MZnz[mi] = bnz;
        return;
    }
    // W transpose
    const int id  = bid - 8192;             // 0..767
    const int z   = id >> 8;
    const int rem = id & 255;
    const int k0  = (rem & 15) * 64, n0 = (rem >> 4) * 64;
    const float* W = (z == 0) ? Wq : (z == 1) ? Wk : Wv;
    ushort* thi = WThi + (size_t)z * D_MODEL * D_MODEL;

    #pragma unroll
    for (int i = 0; i < 4; i++) {
        const int f = i * 256 + t, r = f >> 4, c = (f & 15) * 4;
        const float4 v = *(const float4*)(W + (size_t)(k0 + r) * D_MODEL + n0 + c);
        T[r][c] = v.x; T[r][c + 1] = v.y; T[r][c + 2] = v.z; T[r][c + 3] = v.w;
    }
    __syncthreads();
    #pragma unroll
    for (int i = 0; i < 4; i++) {
        const int f = i * 256 + t, nr = f >> 4, kc = (f & 15) * 4;
        ushort4 h;
        h.x = f2bf(T[kc + 0][nr]);
        h.y = f2bf(T[kc + 1][nr]);
        h.z = f2bf(T[kc + 2][nr]);
        h.w = f2bf(T[kc + 3][nr]);
        const size_t o = (size_t)(n0 + nr) * D_MODEL + k0 + kc;
        *(ushort4*)(thi + o) = h;
    }
}

// ---------------------------------------------------------------------------
// Kernel 3: bf16x2 GEMM 128x128xBK32 + bias + RoPE epilogue.
// global_load_lds width-16, linear double-buffered LDS, 2-phase prefetch,
// ONE barrier per K-step, chunk-XOR swizzle both sides (rule #21), 1-D grid
// with XCD swizzle (T1).  R8: block 0 additionally OR-reduces MZnz -> Flag
// (prep finished before us; attn starts after us -> race-free).
// ---------------------------------------------------------------------------
#define BK 32   // K-step; one LDS row = 32 bf16 = 64B = 4 chunks of 16B

union GemmSM {
    ushort st[2][3][128 * BK];   // [buf][ahi,alo,bhi][row*BK+col]  = 48 KB
    float  c[64 * 132];          // epilogue scratch (33.8 KB)
};

__global__ __launch_bounds__(256, 3)
void gemm_qkv(const ushort* __restrict__ Ahi, const ushort* __restrict__ Alo,
              const ushort* __restrict__ WThi,
              const float* __restrict__ bq, const float* __restrict__ bk,
              const float* __restrict__ bv, const float* __restrict__ temporal,
              const int* __restrict__ MZnz, int* __restrict__ Flag,
              ushort* __restrict__ Qhi, ushort* __restrict__ Qlo,
              ushort* __restrict__ Khi,
              ushort* __restrict__ VT)
{
    __shared__ GemmSM sm;
    __shared__ int flg;
    // XCD swizzle: bidl%8 = XCD slot; XCD x gets m-slabs 4x..4x+3 for all n,z
    const int bidl = blockIdx.x;                 // 0..767
    const int xcd  = bidl & 7, kk = bidl >> 3;   // kk 0..95
    const int m0   = (xcd * 4 + (kk & 3)) * 128;
    const int nz   = kk >> 2;                    // 0..23
    const int n0   = (nz & 7) * 128;
    const int z    = nz >> 3;

    const int t = threadIdx.x;

    if (bidl == 0) {      // mask-zero flag reduce (16 KB read, one block)
        if (t == 0) flg = 0;
        __syncthreads();
        int acc = 0;
        const int4* z4 = (const int4*)MZnz;
        #pragma unroll
        for (int i = 0; i < 4; i++) {
            const int4 v = z4[t * 4 + i];
            acc |= v.x | v.y | v.z | v.w;
        }
        if (acc) atomicOr(&flg, 1);
        __syncthreads();
        if (t == 0) Flag[0] = flg;
    }

    const float* bias = (z == 0) ? bq : (z == 1) ? bk : bv;
    const ushort* Bh = WThi + (size_t)z * D_MODEL * D_MODEL;

    const int w = t >> 6, lane = t & 63;
    const int lane15 = lane & 15, quad8 = (lane >> 4) * 8, quad = lane >> 4;
    const int wm = (w >> 1) * 64, wn = (w & 1) * 64;

    ffrag acc[4][4];
    #pragma unroll
    for (int i = 0; i < 4; i++)
        #pragma unroll
        for (int j = 0; j < 4; j++) acc[i][j] = (ffrag){0.f, 0.f, 0.f, 0.f};

    // DMA staging: lane i of a 16-row chunk covers row (i>>2); its LDS slot is
    // physical chunk (i&3), so it must FETCH logical chunk (i&3)^((i>>3)&3).
    const int wr = w * 32;                                  // wave's 32-row slab
    const int lr = lane >> 2;                               // row within chunk
    const int lc = (((lane & 3) ^ ((lane >> 3) & 3))) * 8;  // swizzled col (elems)

    auto stage = [&](int bsel, int k0) {
        #pragma unroll
        for (int ch = 0; ch < 2; ch++) {
            const int rb = wr + ch * 16;
            const ushort* ga = Ahi + (size_t)(m0 + rb + lr) * D_MODEL + k0 + lc;
            const ushort* gl = Alo + (size_t)(m0 + rb + lr) * D_MODEL + k0 + lc;
            const ushort* gb = Bh  + (size_t)(n0 + rb + lr) * D_MODEL + k0 + lc;
            gload16(ga, &sm.st[bsel][0][rb * BK]);
            gload16(gl, &sm.st[bsel][1][rb * BK]);
            gload16(gb, &sm.st[bsel][2][rb * BK]);
        }
    };

    stage(0, 0);
    __syncthreads();    // drains vmcnt(0): buf0 ready

    // read-side swizzle: logical chunk 'quad' at row (16-aligned + lane15)
    const int rdsw = (quad ^ ((lane15 >> 1) & 3)) * 8;

    int buf = 0;
    for (int k0 = 0; k0 < D_MODEL; k0 += BK) {
        // issue next tile's async loads before computing this one
        if (k0 + BK < D_MODEL) stage(buf ^ 1, k0 + BK);

        bfrag ah[4], al[4];
        #pragma unroll
        for (int mt = 0; mt < 4; mt++) {
            ah[mt] = *(const bfrag*)&sm.st[buf][0][(wm + mt * 16 + lane15) * BK + rdsw];
            al[mt] = *(const bfrag*)&sm.st[buf][1][(wm + mt * 16 + lane15) * BK + rdsw];
        }
        #pragma unroll
        for (int nt = 0; nt < 4; nt++) {
            const bfrag bh = *(const bfrag*)&sm.st[buf][2][(wn + nt * 16 + lane15) * BK + rdsw];
            #pragma unroll
            for (int mt = 0; mt < 4; mt++) {
                ffrag a = acc[mt][nt];
                a = __builtin_amdgcn_mfma_f32_16x16x32_bf16(ah[mt], bh, a, 0, 0, 0);
                a = __builtin_amdgcn_mfma_f32_16x16x32_bf16(al[mt], bh, a, 0, 0, 0);
                acc[mt][nt] = a;
            }
        }
        __syncthreads();   // drains next-tile DMA + orders reads vs overwrite
        buf ^= 1;
    }

    float bn[4];
    #pragma unroll
    for (int nt = 0; nt < 4; nt++) bn[nt] = bias[n0 + wn + nt * 16 + lane15];

    const int CST = (z == 2) ? 129 : 132;

    #pragma unroll
    for (int p = 0; p < 2; p++) {
        if (p) __syncthreads();
        if ((w >> 1) == p) {
            #pragma unroll
            for (int mt = 0; mt < 4; mt++)
                #pragma unroll
                for (int nt = 0; nt < 4; nt++)
                    #pragma unroll
                    for (int rr = 0; rr < 4; rr++)
                        sm.c[(mt * 16 + quad * 4 + rr) * CST + wn + nt * 16 + lane15] =
                            acc[mt][nt][rr] + bn[nt];
        }
        __syncthreads();

        if (z < 2) {
            ushort* ohi = (z == 0) ? Qhi : Khi;
            const float sc = (z == 0) ? 0.125f : 1.0f;
            #pragma unroll
            for (int i = 0; i < 8; i++) {
                const int f = i * 256 + t, r = f >> 5, c4 = (f & 31) * 4;
                float4 v = *(float4*)&sm.c[r * 132 + c4];
                const int m = m0 + p * 64 + r;
                const float tv = temporal[m];
                const float fr0 = exp2f(-(float)(c4 & 63) * FREQ_LOG2);
                const float fr1 = exp2f(-(float)((c4 + 2) & 63) * FREQ_LOG2);
                float s0, c0, s1, c1v;
                __sincosf(tv * fr0, &s0, &c0);
                __sincosf(tv * fr1, &s1, &c1v);
                const float y0 = (v.x * c0 - v.y * s0) * sc;
                const float y1 = (v.y * c0 + v.x * s0) * sc;
                const float y2 = (v.z * c1v - v.w * s1) * sc;
                const float y3 = (v.w * c1v + v.z * s1) * sc;
                ushort4 h, l;
                split_bf(y0, h.x, l.x); split_bf(y1, h.y, l.y);
                split_bf(y2, h.z, l.z); split_bf(y3, h.w, l.w);
                const size_t o = (size_t)m * D_MODEL + n0 + c4;
                *(ushort4*)(ohi + o) = h;
                if (z == 0) *(ushort4*)(Qlo + o) = l;   // K needs no lo
            }
        } else {
            const int bb = m0 >> 11;
            #pragma unroll
            for (int i = 0; i < 4; i++) {
                const int cid = i * 256 + t, col = cid >> 3, tg = (cid & 7) * 8;
                ushort u8[8];
                #pragma unroll
                for (int j = 0; j < 8; j++) u8[j] = f2bf(sm.c[(tg + j) * 129 + col]);
                const int ncol = n0 + col, hh = ncol >> 6, d = ncol & 63;
                const size_t dst = ((size_t)(bb * NHEAD + hh) * HEAD_DIM + d) * SEQ +
                                   (m0 & (SEQ - 1)) + p * 64 + tg;
                *(int4*)(VT + dst) = *(int4*)u8;
            }
        }
    }
}

// ---------------------------------------------------------------------------
// Kernel 4: MFMA flash attention, streaming softmax, QBLK=128, double-buffered
// K/V, ONE barrier per KV tile, XOR chunk swizzle (rule #21), setprio (T5).
// R8: mask-zero fast path — when Flag==0 (mask all zeros), skip the 32 scalar
// mask loads + adds per wave-tile (bitwise-exact: expf(s+0.0f) == expf(s)).
// ---------------------------------------------------------------------------
__global__ __launch_bounds__(256, 2)
void attn_mfma(const ushort* __restrict__ Qhi, const ushort* __restrict__ Qlo,
               const ushort* __restrict__ Khi,
               const ushort* __restrict__ VT,  const ushort* __restrict__ maskbf,
               const int* __restrict__ Flag,
               float* __restrict__ out)
{
    __shared__ ushort lsK[2][64 * 64], lsV[2][64 * 64], lsP[128 * 64];

    const int bid  = blockIdx.x;
    const int bh   = (bid & 7) * 4 + (bid >> 7);
    const int qb   = (bid >> 3) & 15;
    const int b    = bh >> 4, h = bh & 15;
    const int q0   = qb * 128;

    const int t = threadIdx.x, w = t >> 6, lane = t & 63;
    const int lane15 = lane & 15, quad = lane >> 4;
    const size_t tok0 = (size_t)b * SEQ;

    const int mz = Flag[0];            // 0 => mask is entirely zero

    // loop-invariant Q fragments (A-layout), 2 subtiles per wave
    bfrag qh[2][2], ql[2][2];
    #pragma unroll
    for (int su = 0; su < 2; su++) {
        const size_t qrow = (tok0 + q0 + w * 32 + su * 16 + lane15) * D_MODEL +
                            h * HEAD_DIM;
        #pragma unroll
        for (int ks = 0; ks < 2; ks++) {
            qh[su][ks] = *(const bfrag*)(Qhi + qrow + ks * 32 + quad * 8);
            ql[su][ks] = *(const bfrag*)(Qlo + qrow + ks * 32 + quad * 8);
        }
    }

    ffrag of[2][4];
    float l_i[2][4];
    #pragma unroll
    for (int su = 0; su < 2; su++)
        #pragma unroll
        for (int nt = 0; nt < 4; nt++) {
            of[su][nt] = (ffrag){0.f, 0.f, 0.f, 0.f};
            l_i[su][nt] = 0.f;
        }

    const int r1 = t >> 3,  c1 = (t & 7) * 8;              // logical col
    const int sw = ((t & 7) ^ (r1 & 7)) * 8;               // swizzled col
    const ushort* Kh0 = Khi + tok0 * D_MODEL + h * HEAD_DIM;
    const ushort* Vt0 = VT + (size_t)(b * NHEAD + h) * HEAD_DIM * SEQ;

    // tile 0 into regs
    int4 pk0 = *(const int4*)(Kh0 + (size_t)r1 * D_MODEL + c1);
    int4 pk1 = *(const int4*)(Kh0 + (size_t)(32 + r1) * D_MODEL + c1);
    int4 pv0 = *(const int4*)(Vt0 + (size_t)r1 * SEQ + c1);
    int4 pv1 = *(const int4*)(Vt0 + (size_t)(32 + r1) * SEQ + c1);

    // tile 0 regs -> buf0
    *(int4*)&lsK[0][r1 * 64 + sw]        = pk0;
    *(int4*)&lsK[0][(32 + r1) * 64 + sw] = pk1;
    *(int4*)&lsV[0][r1 * 64 + sw]        = pv0;
    *(int4*)&lsV[0][(32 + r1) * 64 + sw] = pv1;

    // tile 1 into regs
    pk0 = *(const int4*)(Kh0 + (size_t)(64 + r1) * D_MODEL + c1);
    pk1 = *(const int4*)(Kh0 + (size_t)(96 + r1) * D_MODEL + c1);
    pv0 = *(const int4*)(Vt0 + (size_t)r1 * SEQ + 64 + c1);
    pv1 = *(const int4*)(Vt0 + (size_t)(32 + r1) * SEQ + 64 + c1);
    __syncthreads();

    const ushort* mrow0 = maskbf + (size_t)(q0 + w * 32 + quad * 4) * SEQ;
    const ushort* mrow1 = maskbf + (size_t)(q0 + w * 32 + 16 + quad * 4) * SEQ;

    const int krd  = lane15 & 7;                                  // K/V rows
    const int keyr = (((lane15 >> 2) & 3) << 1) | (lane15 & 1);   // P rows

    int cur = 0;
    for (int kt = 0; kt < SEQ; kt += 64) {
        // 1) regs (tile kt+64) -> buf cur^1
        if (kt + 64 < SEQ) {
            *(int4*)&lsK[cur ^ 1][r1 * 64 + sw]        = pk0;
            *(int4*)&lsK[cur ^ 1][(32 + r1) * 64 + sw] = pk1;
            *(int4*)&lsV[cur ^ 1][r1 * 64 + sw]        = pv0;
            *(int4*)&lsV[cur ^ 1][(32 + r1) * 64 + sw] = pv1;
        }

        // 2) mask (bf16) for THIS tile — only when mask has nonzeros
        float mv0[4][4], mv1[4][4];
        if (mz) {
            #pragma unroll
            for (int nt = 0; nt < 4; nt++)
                #pragma unroll
                for (int rr = 0; rr < 4; rr++) {
                    mv0[nt][rr] = bf2f(mrow0[(size_t)rr * SEQ + kt + nt * 16 + lane15]);
                    mv1[nt][rr] = bf2f(mrow1[(size_t)rr * SEQ + kt + nt * 16 + lane15]);
                }
        }

        // 3) global prefetch tile kt+128
        const int ktn = (kt + 128 < SEQ) ? kt + 128 : 0;
        pk0 = *(const int4*)(Kh0 + (size_t)(ktn + r1) * D_MODEL + c1);
        pk1 = *(const int4*)(Kh0 + (size_t)(ktn + 32 + r1) * D_MODEL + c1);
        pv0 = *(const int4*)(Vt0 + (size_t)r1 * SEQ + ktn + c1);
        pv1 = *(const int4*)(Vt0 + (size_t)(32 + r1) * SEQ + ktn + c1);

        // 4) S = (Q/8) K^T for both subtiles; kf read ONCE per nt
        ffrag s0[4], s1[4];
        __builtin_amdgcn_s_setprio(1);
        #pragma unroll
        for (int nt = 0; nt < 4; nt++) {
            const bfrag kf0 = *(const bfrag*)&lsK[cur][(nt * 16 + lane15) * 64 +
                                                       ((0 + quad) ^ krd) * 8];
            const bfrag kf1 = *(const bfrag*)&lsK[cur][(nt * 16 + lane15) * 64 +
                                                       ((4 + quad) ^ krd) * 8];
            ffrag a0 = (ffrag){0.f, 0.f, 0.f, 0.f};
            ffrag a1 = (ffrag){0.f, 0.f, 0.f, 0.f};
            a0 = __builtin_amdgcn_mfma_f32_16x16x32_bf16(qh[0][0], kf0, a0, 0, 0, 0);
            a0 = __builtin_amdgcn_mfma_f32_16x16x32_bf16(ql[0][0], kf0, a0, 0, 0, 0);
            a0 = __builtin_amdgcn_mfma_f32_16x16x32_bf16(qh[0][1], kf1, a0, 0, 0, 0);
            a0 = __builtin_amdgcn_mfma_f32_16x16x32_bf16(ql[0][1], kf1, a0, 0, 0, 0);
            a1 = __builtin_amdgcn_mfma_f32_16x16x32_bf16(qh[1][0], kf0, a1, 0, 0, 0);
            a1 = __builtin_amdgcn_mfma_f32_16x16x32_bf16(ql[1][0], kf0, a1, 0, 0, 0);
            a1 = __builtin_amdgcn_mfma_f32_16x16x32_bf16(qh[1][1], kf1, a1, 0, 0, 0);
            a1 = __builtin_amdgcn_mfma_f32_16x16x32_bf16(ql[1][1], kf1, a1, 0, 0, 0);
            s0[nt] = a0;
            s1[nt] = a1;
        }
        __builtin_amdgcn_s_setprio(0);

        // 5) streaming softmax: exp, per-lane l partials, P^T -> swizzled LDS
        #pragma unroll
        for (int nt = 0; nt < 4; nt++)
            #pragma unroll
            for (int rr = 0; rr < 4; rr++) {
                const int pchk = (2 * nt + (lane15 >> 3)) ^ ((quad << 1) | (rr & 1));
                float x0 = s0[nt][rr];
                float x1 = s1[nt][rr];
                if (mz) { x0 += mv0[nt][rr]; x1 += mv1[nt][rr]; }
                const float e0 = __expf(x0);
                l_i[0][rr] += e0;
                lsP[(w * 32 + quad * 4 + rr) * 64 + pchk * 8 + (lane15 & 7)] = f2bf(e0);
                const float e1 = __expf(x1);
                l_i[1][rr] += e1;
                lsP[(w * 32 + 16 + quad * 4 + rr) * 64 + pchk * 8 + (lane15 & 7)] = f2bf(e1);
            }

        // 6) O += P V  (P rows are wave-private: no barrier); vf read ONCE
        __builtin_amdgcn_s_setprio(1);
        #pragma unroll
        for (int ks = 0; ks < 2; ks++) {
            const bfrag pf0 = *(const bfrag*)&lsP[(w * 32 + lane15) * 64 +
                                                  ((ks * 4 + quad) ^ keyr) * 8];
            const bfrag pf1 = *(const bfrag*)&lsP[(w * 32 + 16 + lane15) * 64 +
                                                  ((ks * 4 + quad) ^ keyr) * 8];
            #pragma unroll
            for (int nt = 0; nt < 4; nt++) {
                const bfrag vf = *(const bfrag*)&lsV[cur][(nt * 16 + lane15) * 64 +
                                                          ((ks * 4 + quad) ^ krd) * 8];
                of[0][nt] = __builtin_amdgcn_mfma_f32_16x16x32_bf16(pf0, vf, of[0][nt], 0, 0, 0);
                of[1][nt] = __builtin_amdgcn_mfma_f32_16x16x32_bf16(pf1, vf, of[1][nt], 0, 0, 0);
            }
        }
        __builtin_amdgcn_s_setprio(0);

        // 7) single barrier per KV tile
        __syncthreads();
        cur ^= 1;
    }

    #pragma unroll
    for (int su = 0; su < 2; su++) {
        float inv[4];
        #pragma unroll
        for (int rr = 0; rr < 4; rr++) {
            float v = l_i[su][rr];
            #pragma unroll
            for (int off = 1; off < 16; off <<= 1) v += __shfl_xor(v, off);
            inv[rr] = 1.0f / v;
        }
        #pragma unroll
        for (int nt = 0; nt < 4; nt++)
            #pragma unroll
            for (int rr = 0; rr < 4; rr++)
                out[(tok0 + q0 + w * 32 + su * 16 + quad * 4 + rr) * D_MODEL +
                    h * HEAD_DIM + nt * 16 + lane15] = of[su][nt][rr] * inv[rr];
    }
}

// ---------------------------------------------------------------------------
extern "C" void kernel_launch(void* const* d_in, const int* in_sizes, int n_in,
                              void* d_out, int out_size, void* d_ws, size_t ws_size,
                              hipStream_t stream)
{
    const float* data     = (const float*)d_in[0];
    const float* temporal = (const float*)d_in[1];
    const float* mask     = (const float*)d_in[2];
    const float* Wq = (const float*)d_in[3];
    const float* bq = (const float*)d_in[4];
    const float* Wk = (const float*)d_in[5];
    const float* bk = (const float*)d_in[6];
    const float* Wv = (const float*)d_in[7];
    const float* bv = (const float*)d_in[8];
    float* out = (float*)d_out;

    char* ws = (char*)d_ws;
    const size_t MB = 1024 * 1024;
    ushort* Ahi  = (ushort*)(ws + 0 * MB);
    ushort* Alo  = (ushort*)(ws + 8 * MB);
    ushort* WThi = (ushort*)(ws + 16 * MB);   // 6 MB (3x1024x1024 bf16)
    int*    MZnz = (int*)   (ws + 22 * MB);   // 16 KB (4096 ints)
    int*    Flag = (int*)   (ws + 23 * MB);   // 4 B
    ushort* Qhi  = (ushort*)(ws + 28 * MB);
    ushort* Qlo  = (ushort*)(ws + 36 * MB);
    ushort* Khi  = (ushort*)(ws + 44 * MB);
    ushort* VT   = (ushort*)(ws + 60 * MB);   // 8 MB
    ushort* Mbf  = (ushort*)(ws + 68 * MB);   // 8 MB (2048x2048 bf16)

    prep<<<dim3(8960), 256, 0, stream>>>(data, Ahi, Alo, mask, Mbf, MZnz,
                                         Wq, Wk, Wv, WThi);
    gemm_qkv<<<dim3(768), 256, 0, stream>>>(
        Ahi, Alo, WThi, bq, bk, bv, temporal, MZnz, Flag,
        Qhi, Qlo, Khi, VT);
    attn_mfma<<<dim3(BATCH * NHEAD * SEQ / 128), 256, 0, stream>>>(
        Qhi, Qlo, Khi, VT, Mbf, Flag, out);
}